// Round 13
// baseline (203.157 us; speedup 1.0000x reference)
//
#include <hip/hip_runtime.h>
#include <math.h>

#define HW 9216
#define C 64
#define BATCH 2
#define K 7
#define NCH 16
#define CHUNK 576            // HW/NCH
#define NOUT 9               // outer steps, 64 rows each
#define P1CH 4               // phase-1 chunks
#define CAP 160              // per-row append capacity (32 p1 + 160 = 192 <= 3*64)
#define IK 448               // K*C contraction length
#define GA_STRIDE 456        // IK + 8

typedef __attribute__((ext_vector_type(8))) short bf16x8;
typedef __attribute__((ext_vector_type(16))) float f32x16;

#define GLOAD_LDS(gp, lp) __builtin_amdgcn_global_load_lds( \
    (const __attribute__((address_space(1))) unsigned int*)(gp), \
    (__attribute__((address_space(3))) unsigned int*)(lp), 16, 0, 0)

__device__ __forceinline__ unsigned umax_(unsigned a, unsigned b) {
#if defined(__has_builtin) && __has_builtin(__builtin_elementwise_max)
    return __builtin_elementwise_max(a, b);
#else
    return a >= b ? a : b;
#endif
}
__device__ __forceinline__ unsigned umin_(unsigned a, unsigned b) {
#if defined(__has_builtin) && __has_builtin(__builtin_elementwise_min)
    return __builtin_elementwise_min(a, b);
#else
    return a >= b ? b : a;
#endif
}

__device__ __forceinline__ unsigned short rne_bf16(float f) {
    unsigned u = __float_as_uint(f);
    unsigned r = u + 0x7fffu + ((u >> 16) & 1u);
    return (unsigned short)(r >> 16);
}

// Batcher odd-even sort-8, descending, 19 CE
__device__ __forceinline__ void sort8_desc(unsigned (&k)[8]) {
#define CE8(i, j) { unsigned hi = umax_(k[i], k[j]); unsigned lo = umin_(k[i], k[j]); k[i] = hi; k[j] = lo; }
    CE8(0,1) CE8(2,3) CE8(4,5) CE8(6,7)
    CE8(0,2) CE8(1,3) CE8(4,6) CE8(5,7)
    CE8(1,2) CE8(5,6)
    CE8(0,4) CE8(1,5) CE8(2,6) CE8(3,7)
    CE8(2,4) CE8(3,5)
    CE8(1,2) CE8(3,4) CE8(5,6)
#undef CE8
}

// bitonic half-cleaner: sorts a bitonic 8-seq descending (12 CE)
__device__ __forceinline__ void clean8_desc(unsigned (&t)[8]) {
#define CET(i, j) { unsigned hi = umax_(t[i], t[j]); unsigned lo = umin_(t[i], t[j]); t[i] = hi; t[j] = lo; }
    CET(0,4) CET(1,5) CET(2,6) CET(3,7)
    CET(0,2) CET(1,3) CET(4,6) CET(5,7)
    CET(0,1) CET(2,3) CET(4,5) CET(6,7)
#undef CET
}

// tv (sorted desc) := top-8 of tv ∪ s (s sorted desc), sorted desc.
__device__ __forceinline__ void merge8_desc(unsigned (&tv)[8], const unsigned (&s)[8]) {
    unsigned t[8];
#pragma unroll
    for (int i = 0; i < 8; ++i) t[i] = umax_(tv[i], s[7 - i]);
    clean8_desc(t);
#pragma unroll
    for (int i = 0; i < 8; ++i) tv[i] = t[i];
}

// ---------------- kernel 1: normalize + transpose + bf16 (+ fused W->bf16 transpose) ----------------
__global__ __launch_bounds__(256) void k_norm(const float* __restrict__ x,
                                              const float* __restrict__ W,
                                              float* __restrict__ XT,
                                              unsigned short* __restrict__ Xhi,
                                              float* __restrict__ invn,
                                              unsigned short* __restrict__ WbT) {
    int b = blockIdx.y, tid = threadIdx.x;
    int bx = blockIdx.x;
    if (bx >= HW / 64) {
        if (b == 0) {
            int base = (bx - HW / 64) * 1024 + tid * 4;
#pragma unroll
            for (int j = 0; j < 4; ++j) {
                int idx = base + j;
                int o = idx / IK;
                int rem = idx - o * IK;
                int kq = rem >> 6, i = rem & 63;
                WbT[idx] = rne_bf16(W[(o * C + i) * K + kq]);
            }
        }
        return;
    }
    int m0 = bx * 64;
    __shared__ float T[64 * 65];
    __shared__ float ps[4][64];
    __shared__ float inv[64];
    const float* xb = x + (size_t)b * C * HW;
    for (int r = 0; r < 16; ++r) {
        int idx = r * 256 + tid; int c = idx >> 6, mm = idx & 63;
        T[c * 65 + mm] = xb[(size_t)c * HW + m0 + mm];
    }
    __syncthreads();
    int ml = tid & 63, part = tid >> 6;
    float s = 0.f;
    for (int c = part * 16; c < part * 16 + 16; ++c) { float v = T[c * 65 + ml]; s += v * v; }
    ps[part][ml] = s;
    __syncthreads();
    if (tid < 64) {
        float tot = ps[0][tid] + ps[1][tid] + ps[2][tid] + ps[3][tid];
        float iv = 1.0f / sqrtf(tot);
        inv[tid] = iv;
        invn[(size_t)b * HW + m0 + tid] = iv;
    }
    __syncthreads();
    for (int r = 0; r < 16; ++r) {
        int idx = r * 256 + tid; int row = idx >> 6, c = idx & 63;
        float uv = T[c * 65 + row];
        XT[((size_t)b * HW + m0 + row) * C + c] = uv;
        Xhi[((size_t)b * HW + m0 + row) * C + c] = rne_bf16(uv * inv[row]);
    }
}

// ---------------- kernel 2a: phase-1 scores (chunks 0..3): sort-merge top-8 per chunk ----------------
__global__ __launch_bounds__(256) void k_score1(const unsigned short* __restrict__ Xhi,
                                                unsigned* __restrict__ candi,
                                                unsigned* __restrict__ cnt) {
    int mg = blockIdx.x, chunk = blockIdx.y, b = blockIdx.z;
    int tid = threadIdx.x;
    if (chunk == 0 && tid < 128) cnt[b * HW + mg * 128 + tid] = 0u;
    int w = tid >> 6, l = tid & 63;
    int lr = l & 31, lh = l >> 5;
    int m = mg * 128 + w * 32 + lr;
    const char* Xb = (const char*)(Xhi + (size_t)b * HW * C);   // 128B rows

    __shared__ __align__(16) char tiles[2][8192];

    bf16x8 bf[4];
#pragma unroll
    for (int t = 0; t < 4; ++t)
        bf[t] = *(const bf16x8*)(Xb + (size_t)m * 128 + t * 32 + lh * 16);

    int swsrc = (tid * 16) ^ (((tid >> 3) & 7) << 4);
    int nC = chunk * CHUNK;

    GLOAD_LDS(Xb + (size_t)nC * 128 + swsrc, &tiles[0][w * 1024]);
    GLOAD_LDS(Xb + (size_t)nC * 128 + 4096 + swsrc, &tiles[0][4096 + w * 1024]);
    __syncthreads();

    unsigned tv[8];
#pragma unroll
    for (int j = 0; j < 8; ++j) tv[j] = 0u;

    const float BIAS = 1.0625f;
    const f32x16 cbias = {BIAS,BIAS,BIAS,BIAS,BIAS,BIAS,BIAS,BIAS,
                          BIAS,BIAS,BIAS,BIAS,BIAS,BIAS,BIAS,BIAS};

    for (int so = 0; so < NOUT; ++so) {
        if (so + 1 < NOUT) {
            const char* src = Xb + (size_t)(nC + (so + 1) * 64) * 128;
            GLOAD_LDS(src + swsrc, &tiles[(so + 1) & 1][w * 1024]);
            GLOAD_LDS(src + 4096 + swsrc, &tiles[(so + 1) & 1][4096 + w * 1024]);
        }
        const char* tile = tiles[so & 1];
#pragma unroll
        for (int h = 0; h < 2; ++h) {
            bf16x8 af0 = *(const bf16x8*)(tile + (h * 32 + lr) * 128 + ((lh * 16) ^ ((lr & 7) << 4)));
            f32x16 acc = __builtin_amdgcn_mfma_f32_32x32x16_bf16(af0, bf[0], cbias, 0, 0, 0);
#pragma unroll
            for (int t = 1; t < 4; ++t) {
                int o = t * 32 + lh * 16;
                bf16x8 af = *(const bf16x8*)(tile + (h * 32 + lr) * 128 + (o ^ ((lr & 7) << 4)));
                acc = __builtin_amdgcn_mfma_f32_32x32x16_bf16(af, bf[t], acc, 0, 0, 0);
            }
            unsigned inv_base = 2047u - (unsigned)(so * 64 + h * 32 + 4 * lh);
            unsigned ka[8], kb[8];
#pragma unroll
            for (int r = 0; r < 8; ++r) {
                ka[r] = (__float_as_uint(acc[r]) & 0xFFFFF800u)
                      | (inv_base - (unsigned)((r & 3) + 8 * (r >> 2)));
                kb[r] = (__float_as_uint(acc[r + 8]) & 0xFFFFF800u)
                      | (inv_base - (unsigned)(((r + 8) & 3) + 8 * ((r + 8) >> 2)));
            }
            sort8_desc(ka);
            sort8_desc(kb);
            merge8_desc(tv, ka);
            merge8_desc(tv, kb);
        }
        __syncthreads();
    }

    // cross-half-lane merge -> bitonic -> CLEAN so the stored list is sorted desc
    unsigned pv[8];
#pragma unroll
    for (int j = 0; j < 8; ++j) pv[j] = tv[j];
#pragma unroll
    for (int j = 0; j < 8; ++j) {
        unsigned o = (unsigned)__shfl_xor((int)pv[7 - j], 32, 64);
        tv[j] = umax_(tv[j], o);
    }
    clean8_desc(tv);
    if (lh == 0) {
        size_t base = ((size_t)(b * HW + m) * P1CH + chunk) * 8;
#pragma unroll
        for (int j = 0; j < 8; ++j) candi[base + j] = tv[j];
    }
}

// ---------------- kernel 2b: phase-2 scores (chunks 4..15): theta-filter + append ----------------
__global__ __launch_bounds__(256) void k_score2(const unsigned short* __restrict__ Xhi,
                                                const unsigned* __restrict__ candi,
                                                unsigned* __restrict__ cnt,
                                                unsigned* __restrict__ glist) {
    int mg = blockIdx.x, chunk = P1CH + blockIdx.y, b = blockIdx.z;
    int tid = threadIdx.x;
    int w = tid >> 6, l = tid & 63;
    int lr = l & 31, lh = l >> 5;
    int m = mg * 128 + w * 32 + lr;
    int g = b * HW + m;
    const char* Xb = (const char*)(Xhi + (size_t)b * HW * C);

    // theta = 8th largest of union of the four sorted-desc phase-1 top-8 lists
    const unsigned* p1 = candi + (size_t)g * (P1CH * 8);
    unsigned t8[8], s8[8];
#pragma unroll
    for (int i = 0; i < 8; ++i) t8[i] = p1[i];
#pragma unroll
    for (int c = 1; c < P1CH; ++c) {
#pragma unroll
        for (int i = 0; i < 8; ++i) s8[i] = p1[c * 8 + i];
        merge8_desc(t8, s8);
    }
    float tf = __uint_as_float(t8[7] & 0xFFFFF800u) - 0.010f;
    unsigned thmb = __float_as_uint(tf);

    __shared__ __align__(16) char tiles[2][8192];

    bf16x8 bf[4];
#pragma unroll
    for (int t = 0; t < 4; ++t)
        bf[t] = *(const bf16x8*)(Xb + (size_t)m * 128 + t * 32 + lh * 16);

    int swsrc = (tid * 16) ^ (((tid >> 3) & 7) << 4);
    int nC = chunk * CHUNK;

    GLOAD_LDS(Xb + (size_t)nC * 128 + swsrc, &tiles[0][w * 1024]);
    GLOAD_LDS(Xb + (size_t)nC * 128 + 4096 + swsrc, &tiles[0][4096 + w * 1024]);
    __syncthreads();

    const float BIAS = 1.0625f;
    const f32x16 cbias = {BIAS,BIAS,BIAS,BIAS,BIAS,BIAS,BIAS,BIAS,
                          BIAS,BIAS,BIAS,BIAS,BIAS,BIAS,BIAS,BIAS};

    for (int so = 0; so < NOUT; ++so) {
        if (so + 1 < NOUT) {
            const char* src = Xb + (size_t)(nC + (so + 1) * 64) * 128;
            GLOAD_LDS(src + swsrc, &tiles[(so + 1) & 1][w * 1024]);
            GLOAD_LDS(src + 4096 + swsrc, &tiles[(so + 1) & 1][4096 + w * 1024]);
        }
        const char* tile = tiles[so & 1];
#pragma unroll
        for (int h = 0; h < 2; ++h) {
            bf16x8 af0 = *(const bf16x8*)(tile + (h * 32 + lr) * 128 + ((lh * 16) ^ ((lr & 7) << 4)));
            f32x16 acc = __builtin_amdgcn_mfma_f32_32x32x16_bf16(af0, bf[0], cbias, 0, 0, 0);
#pragma unroll
            for (int t = 1; t < 4; ++t) {
                int o = t * 32 + lh * 16;
                bf16x8 af = *(const bf16x8*)(tile + (h * 32 + lr) * 128 + (o ^ ((lr & 7) << 4)));
                acc = __builtin_amdgcn_mfma_f32_32x32x16_bf16(af, bf[t], acc, 0, 0, 0);
            }
            int nbase = nC + so * 64 + h * 32 + 4 * lh;
#pragma unroll
            for (int r = 0; r < 16; ++r) {
                unsigned hb = __float_as_uint(acc[r]);
                bool hit = hb > thmb;
                if (__any(hit)) {
                    if (hit) {
                        unsigned pos = atomicAdd(&cnt[g], 1u);
                        if (pos < CAP) {
                            unsigned nglob = (unsigned)(nbase + (r & 3) + 8 * (r >> 2));
                            glist[(size_t)g * CAP + pos] = (hb & 0xFFFFC000u) | nglob;
                        }
                    }
                }
            }
        }
        __syncthreads();
    }
}

// ---------------- kernel 3: threshold-pruned exact fp32 rescore over p1 + appended records ----------------
__global__ __launch_bounds__(256) void k_rescore(const float* __restrict__ XT,
                                                 const float* __restrict__ invn,
                                                 const unsigned* __restrict__ candi,
                                                 const unsigned* __restrict__ cnt,
                                                 const unsigned* __restrict__ glist,
                                                 float* __restrict__ fvals,
                                                 int* __restrict__ fidx) {
    int g = blockIdx.x * 4 + (threadIdx.x >> 6);
    int l = threadIdx.x & 63;
    int b = g / HW, m = g - b * HW;
    const float* Xb = XT + (size_t)b * HW * C;
    float xml = Xb[(size_t)m * C + l];
    float vm = invn[g];

    int cn = (int)cnt[g];
    cn = cn < CAP ? cn : CAP;

    // 3 record slots/lane: idx = h*64 + l; idx<32 -> p1 (as set), else glist[idx-32]
    unsigned kr[3];
#pragma unroll
    for (int h = 0; h < 3; ++h) {
        int idx = h * 64 + l;
        if (idx < P1CH * 8) {
            unsigned key = candi[(size_t)g * (P1CH * 8) + idx];
            unsigned n = (unsigned)((idx >> 3) * CHUNK + (2047 - (int)(key & 0x7FFu)));
            kr[h] = (key & 0xFFFFC000u) | n;
        } else {
            int j = idx - P1CH * 8;
            kr[h] = (j < cn) ? glist[(size_t)g * CAP + j] : 0u;
        }
    }

    // radix search over score bits [30:14]: largest prefix with count >= 7
    unsigned thr = 0u;
#pragma unroll
    for (int bit = 30; bit >= 14; --bit) {
        unsigned cand = thr | (1u << bit);
        int c2 = __popcll(__ballot(kr[0] >= cand))
               + __popcll(__ballot(kr[1] >= cand))
               + __popcll(__ballot(kr[2] >= cand));
        if (c2 >= 7) thr = cand;
    }
    float s7 = __uint_as_float(thr);
    unsigned thk = __float_as_uint(s7 - 0.016f) & 0xFFFFC000u;

    float svv = -1e30f; int svi = 0x7fffffff;
    int nsurv = 0;
#pragma unroll
    for (int h = 0; h < 3; ++h) {
        unsigned long long bb = __ballot(kr[h] >= thk);
        while (bb) {
            int src = __builtin_ctzll(bb);
            bb &= bb - 1;
            unsigned key = (unsigned)__shfl((int)kr[h], src, 64);
            int ci = (int)(key & 0x3FFFu);
            float v = xml * Xb[(size_t)ci * C + l];
            v += __shfl_xor(v, 1, 64);  v += __shfl_xor(v, 2, 64);
            v += __shfl_xor(v, 4, 64);  v += __shfl_xor(v, 8, 64);
            v += __shfl_xor(v, 16, 64); v += __shfl_xor(v, 32, 64);
            if (l == nsurv) { svv = v * vm * invn[(size_t)b * HW + ci]; svi = ci; }
            ++nsurv;
        }
    }

    for (int s = 0; s < 7; ++s) {
        float bv = svv; int bi = svi;
#pragma unroll
        for (int d = 1; d < 64; d <<= 1) {
            float ov = __shfl_xor(bv, d, 64);
            int   oi = __shfl_xor(bi, d, 64);
            if (ov > bv || (ov == bv && oi < bi)) { bv = ov; bi = oi; }
        }
        if (l == 0) { fvals[(size_t)g * 7 + s] = bv; fidx[(size_t)g * 7 + s] = bi; }
        if (svi == bi) svv = -1e30f;
    }
}

// ---------------- kernel 4: bf16-MFMA conv: gather->LDS, D = Ga(64x448) x WbT^T(448x64) ----------------
__global__ __launch_bounds__(256) void k_out(const float* __restrict__ XT,
                                             const unsigned short* __restrict__ WbT,
                                             const float* __restrict__ fvals,
                                             const int* __restrict__ fidx,
                                             const float* __restrict__ bias,
                                             float* __restrict__ out) {
    int b = blockIdx.y;
    int m0 = blockIdx.x * 64;
    int tid = threadIdx.x;
    int w = tid >> 6, l = tid & 63;
    int lr = l & 31, hi = l >> 5;

    __shared__ __align__(16) unsigned short Ga[64][GA_STRIDE];  // 58.4 KB, bf16 [m][ik]
    __shared__ float Red[64][68];                               // 17.4 KB  [o][m]
    __shared__ int   fiL[64 * K];
    __shared__ float fvL[64 * K];

#pragma unroll
    for (int t = 0; t < 2; ++t) {
        int idx = t * 256 + tid;
        if (idx < 64 * K) {
            int gm = (b * HW + m0 + (idx / K)) * K + (idx % K);
            fiL[idx] = fidx[gm];
            fvL[idx] = fvals[gm];
        }
    }
    __syncthreads();

#pragma unroll
    for (int t = 0; t < 28; ++t) {
        int slot = t * 256 + tid;              // 7168 slots
        int r = slot >> 4, i4 = slot & 15;     // r = kq*64 + m
        int m = r & 63, kq = r >> 6;
        int n = fiL[m * K + kq];
        float vv = fvL[m * K + kq];
        float4 g = *(const float4*)&XT[((size_t)b * HW + n) * C + i4 * 4];
        unsigned short h0 = rne_bf16(g.x * vv), h1 = rne_bf16(g.y * vv);
        unsigned short h2 = rne_bf16(g.z * vv), h3 = rne_bf16(g.w * vv);
        unsigned p0 = (unsigned)h0 | ((unsigned)h1 << 16);
        unsigned p1 = (unsigned)h2 | ((unsigned)h3 << 16);
        uint2 p = {p0, p1};
        *(uint2*)&Ga[m][kq * 64 + i4 * 4] = p;
    }
    __syncthreads();

    int mt = w & 1, ct = w >> 1;
    int arow = mt * 32 + lr;
    int ocol = ct * 32 + lr;
    float bv = bias[ocol];
    f32x16 acc;
#pragma unroll
    for (int r = 0; r < 16; ++r) acc[r] = bv;

    const unsigned short* wrow = WbT + (size_t)ocol * IK;
#pragma unroll
    for (int s = 0; s < 28; ++s) {
        bf16x8 af = *(const bf16x8*)&Ga[arow][s * 16 + hi * 8];
        bf16x8 bf = *(const bf16x8*)&wrow[s * 16 + hi * 8];
        acc = __builtin_amdgcn_mfma_f32_32x32x16_bf16(af, bf, acc, 0, 0, 0);
    }

#pragma unroll
    for (int j = 0; j < 4; ++j) {
        float4 r4 = {acc[j * 4 + 0], acc[j * 4 + 1], acc[j * 4 + 2], acc[j * 4 + 3]};
        *(float4*)&Red[ocol][mt * 32 + j * 8 + hi * 4] = r4;
    }
    __syncthreads();

#pragma unroll
    for (int t = 0; t < 4; ++t) {
        int slot4 = t * 256 + tid;             // 1024 float4
        int o = slot4 >> 4, m4 = slot4 & 15;
        float4 v = *(const float4*)&Red[o][m4 * 4];
        v.x = v.x > 0.f ? v.x : 0.f;
        v.y = v.y > 0.f ? v.y : 0.f;
        v.z = v.z > 0.f ? v.z : 0.f;
        v.w = v.w > 0.f ? v.w : 0.f;
        *(float4*)&out[((size_t)b * C + o) * HW + m0 + m4 * 4] = v;
    }
}

extern "C" void kernel_launch(void* const* d_in, const int* in_sizes, int n_in,
                              void* d_out, int out_size, void* d_ws, size_t ws_size,
                              hipStream_t stream) {
    const float* x = (const float*)d_in[0];
    const float* W = (const float*)d_in[1];
    const float* bias = (const float*)d_in[2];
    float* out = (float*)d_out;

    float* ws = (float*)d_ws;
    float* XT = ws;                                        // B*HW*C f32
    unsigned short* Xhi = (unsigned short*)(XT + (size_t)BATCH * HW * C);   // B*HW*C bf16
    float* invn = (float*)(Xhi + (size_t)BATCH * HW * C);  // B*HW
    unsigned short* WbT = (unsigned short*)(invn + (size_t)BATCH * HW);     // C*IK bf16
    unsigned* candi = (unsigned*)(WbT + (size_t)C * IK + 64);               // B*HW*32 p1 keys
    unsigned* cnt = candi + (size_t)BATCH * HW * (P1CH * 8);                // B*HW
    unsigned* glist = cnt + (size_t)BATCH * HW;                             // B*HW*CAP
    float* fvals = (float*)(glist + (size_t)BATCH * HW * CAP);
    int* fidx = (int*)(fvals + (size_t)BATCH * HW * K);

    k_norm<<<dim3(HW / 64 + 28, BATCH), 256, 0, stream>>>(x, W, XT, Xhi, invn, WbT);
    k_score1<<<dim3(HW / 128, P1CH, BATCH), 256, 0, stream>>>(Xhi, candi, cnt);
    k_score2<<<dim3(HW / 128, NCH - P1CH, BATCH), 256, 0, stream>>>(Xhi, candi, cnt, glist);
    k_rescore<<<dim3(BATCH * HW / 4), 256, 0, stream>>>(XT, invn, candi, cnt, glist, fvals, fidx);
    k_out<<<dim3(HW / 64, BATCH), 256, 0, stream>>>(XT, WbT, fvals, fidx, bias, out);
}

// Round 14
// 146.920 us; speedup vs baseline: 1.3828x; 1.3828x over previous
//
#include <hip/hip_runtime.h>
#include <math.h>

#define HW 9216
#define C 64
#define BATCH 2
#define K 7
#define NCH 16
#define CHUNK 576            // HW/NCH
#define NOUT 9               // outer steps, 64 rows each
#define P1CH 4               // phase-1 chunks
#define CAP 160              // per-row global append capacity
#define LCAP 32              // per-row per-chunk LDS append capacity
#define IK 448               // K*C contraction length
#define GA_STRIDE 456        // IK + 8

typedef __attribute__((ext_vector_type(8))) short bf16x8;
typedef __attribute__((ext_vector_type(16))) float f32x16;

#define GLOAD_LDS(gp, lp) __builtin_amdgcn_global_load_lds( \
    (const __attribute__((address_space(1))) unsigned int*)(gp), \
    (__attribute__((address_space(3))) unsigned int*)(lp), 16, 0, 0)

__device__ __forceinline__ unsigned umax_(unsigned a, unsigned b) {
#if defined(__has_builtin) && __has_builtin(__builtin_elementwise_max)
    return __builtin_elementwise_max(a, b);
#else
    return a >= b ? a : b;
#endif
}
__device__ __forceinline__ unsigned umin_(unsigned a, unsigned b) {
#if defined(__has_builtin) && __has_builtin(__builtin_elementwise_min)
    return __builtin_elementwise_min(a, b);
#else
    return a >= b ? b : a;
#endif
}

__device__ __forceinline__ unsigned short rne_bf16(float f) {
    unsigned u = __float_as_uint(f);
    unsigned r = u + 0x7fffu + ((u >> 16) & 1u);
    return (unsigned short)(r >> 16);
}

// Batcher odd-even sort-8, descending, 19 CE
__device__ __forceinline__ void sort8_desc(unsigned (&k)[8]) {
#define CE8(i, j) { unsigned hi = umax_(k[i], k[j]); unsigned lo = umin_(k[i], k[j]); k[i] = hi; k[j] = lo; }
    CE8(0,1) CE8(2,3) CE8(4,5) CE8(6,7)
    CE8(0,2) CE8(1,3) CE8(4,6) CE8(5,7)
    CE8(1,2) CE8(5,6)
    CE8(0,4) CE8(1,5) CE8(2,6) CE8(3,7)
    CE8(2,4) CE8(3,5)
    CE8(1,2) CE8(3,4) CE8(5,6)
#undef CE8
}

// bitonic half-cleaner: sorts a bitonic 8-seq descending (12 CE)
__device__ __forceinline__ void clean8_desc(unsigned (&t)[8]) {
#define CET(i, j) { unsigned hi = umax_(t[i], t[j]); unsigned lo = umin_(t[i], t[j]); t[i] = hi; t[j] = lo; }
    CET(0,4) CET(1,5) CET(2,6) CET(3,7)
    CET(0,2) CET(1,3) CET(4,6) CET(5,7)
    CET(0,1) CET(2,3) CET(4,5) CET(6,7)
#undef CET
}

// tv (sorted desc) := top-8 of tv ∪ s (s sorted desc), sorted desc.
__device__ __forceinline__ void merge8_desc(unsigned (&tv)[8], const unsigned (&s)[8]) {
    unsigned t[8];
#pragma unroll
    for (int i = 0; i < 8; ++i) t[i] = umax_(tv[i], s[7 - i]);
    clean8_desc(t);
#pragma unroll
    for (int i = 0; i < 8; ++i) tv[i] = t[i];
}

// ---------------- kernel 1: normalize + transpose + bf16 (+ fused W->bf16 transpose) ----------------
__global__ __launch_bounds__(256) void k_norm(const float* __restrict__ x,
                                              const float* __restrict__ W,
                                              float* __restrict__ XT,
                                              unsigned short* __restrict__ Xhi,
                                              float* __restrict__ invn,
                                              unsigned short* __restrict__ WbT) {
    int b = blockIdx.y, tid = threadIdx.x;
    int bx = blockIdx.x;
    if (bx >= HW / 64) {
        if (b == 0) {
            int base = (bx - HW / 64) * 1024 + tid * 4;
#pragma unroll
            for (int j = 0; j < 4; ++j) {
                int idx = base + j;
                int o = idx / IK;
                int rem = idx - o * IK;
                int kq = rem >> 6, i = rem & 63;
                WbT[idx] = rne_bf16(W[(o * C + i) * K + kq]);
            }
        }
        return;
    }
    int m0 = bx * 64;
    __shared__ float T[64 * 65];
    __shared__ float ps[4][64];
    __shared__ float inv[64];
    const float* xb = x + (size_t)b * C * HW;
    for (int r = 0; r < 16; ++r) {
        int idx = r * 256 + tid; int c = idx >> 6, mm = idx & 63;
        T[c * 65 + mm] = xb[(size_t)c * HW + m0 + mm];
    }
    __syncthreads();
    int ml = tid & 63, part = tid >> 6;
    float s = 0.f;
    for (int c = part * 16; c < part * 16 + 16; ++c) { float v = T[c * 65 + ml]; s += v * v; }
    ps[part][ml] = s;
    __syncthreads();
    if (tid < 64) {
        float tot = ps[0][tid] + ps[1][tid] + ps[2][tid] + ps[3][tid];
        float iv = 1.0f / sqrtf(tot);
        inv[tid] = iv;
        invn[(size_t)b * HW + m0 + tid] = iv;
    }
    __syncthreads();
    for (int r = 0; r < 16; ++r) {
        int idx = r * 256 + tid; int row = idx >> 6, c = idx & 63;
        float uv = T[c * 65 + row];
        XT[((size_t)b * HW + m0 + row) * C + c] = uv;
        Xhi[((size_t)b * HW + m0 + row) * C + c] = rne_bf16(uv * inv[row]);
    }
}

// ---------------- kernel 2a: phase-1 scores (chunks 0..3): sort-merge top-8 per chunk ----------------
__global__ __launch_bounds__(256) void k_score1(const unsigned short* __restrict__ Xhi,
                                                unsigned* __restrict__ candi,
                                                unsigned* __restrict__ cnt) {
    int mg = blockIdx.x, chunk = blockIdx.y, b = blockIdx.z;
    int tid = threadIdx.x;
    if (chunk == 0 && tid < 128) cnt[b * HW + mg * 128 + tid] = 0u;
    int w = tid >> 6, l = tid & 63;
    int lr = l & 31, lh = l >> 5;
    int m = mg * 128 + w * 32 + lr;
    const char* Xb = (const char*)(Xhi + (size_t)b * HW * C);   // 128B rows

    __shared__ __align__(16) char tiles[2][8192];

    bf16x8 bf[4];
#pragma unroll
    for (int t = 0; t < 4; ++t)
        bf[t] = *(const bf16x8*)(Xb + (size_t)m * 128 + t * 32 + lh * 16);

    int swsrc = (tid * 16) ^ (((tid >> 3) & 7) << 4);
    int nC = chunk * CHUNK;

    GLOAD_LDS(Xb + (size_t)nC * 128 + swsrc, &tiles[0][w * 1024]);
    GLOAD_LDS(Xb + (size_t)nC * 128 + 4096 + swsrc, &tiles[0][4096 + w * 1024]);
    __syncthreads();

    unsigned tv[8];
#pragma unroll
    for (int j = 0; j < 8; ++j) tv[j] = 0u;

    const float BIAS = 1.0625f;
    const f32x16 cbias = {BIAS,BIAS,BIAS,BIAS,BIAS,BIAS,BIAS,BIAS,
                          BIAS,BIAS,BIAS,BIAS,BIAS,BIAS,BIAS,BIAS};

    for (int so = 0; so < NOUT; ++so) {
        if (so + 1 < NOUT) {
            const char* src = Xb + (size_t)(nC + (so + 1) * 64) * 128;
            GLOAD_LDS(src + swsrc, &tiles[(so + 1) & 1][w * 1024]);
            GLOAD_LDS(src + 4096 + swsrc, &tiles[(so + 1) & 1][4096 + w * 1024]);
        }
        const char* tile = tiles[so & 1];
#pragma unroll
        for (int h = 0; h < 2; ++h) {
            bf16x8 af0 = *(const bf16x8*)(tile + (h * 32 + lr) * 128 + ((lh * 16) ^ ((lr & 7) << 4)));
            f32x16 acc = __builtin_amdgcn_mfma_f32_32x32x16_bf16(af0, bf[0], cbias, 0, 0, 0);
#pragma unroll
            for (int t = 1; t < 4; ++t) {
                int o = t * 32 + lh * 16;
                bf16x8 af = *(const bf16x8*)(tile + (h * 32 + lr) * 128 + (o ^ ((lr & 7) << 4)));
                acc = __builtin_amdgcn_mfma_f32_32x32x16_bf16(af, bf[t], acc, 0, 0, 0);
            }
            unsigned inv_base = 2047u - (unsigned)(so * 64 + h * 32 + 4 * lh);
            unsigned ka[8], kb[8];
#pragma unroll
            for (int r = 0; r < 8; ++r) {
                ka[r] = (__float_as_uint(acc[r]) & 0xFFFFF800u)
                      | (inv_base - (unsigned)((r & 3) + 8 * (r >> 2)));
                kb[r] = (__float_as_uint(acc[r + 8]) & 0xFFFFF800u)
                      | (inv_base - (unsigned)(((r + 8) & 3) + 8 * ((r + 8) >> 2)));
            }
            sort8_desc(ka);
            sort8_desc(kb);
            merge8_desc(tv, ka);
            merge8_desc(tv, kb);
        }
        __syncthreads();
    }

    // cross-half-lane merge -> bitonic -> clean so the stored list is sorted desc
    unsigned pv[8];
#pragma unroll
    for (int j = 0; j < 8; ++j) pv[j] = tv[j];
#pragma unroll
    for (int j = 0; j < 8; ++j) {
        unsigned o = (unsigned)__shfl_xor((int)pv[7 - j], 32, 64);
        tv[j] = umax_(tv[j], o);
    }
    clean8_desc(tv);
    if (lh == 0) {
        size_t base = ((size_t)(b * HW + m) * P1CH + chunk) * 8;
#pragma unroll
        for (int j = 0; j < 8; ++j) candi[base + j] = tv[j];
    }
}

// ---------------- kernel 2b: phase-2 (chunks 4..15): theta-filter + LDS-buffered append ----------------
__global__ __launch_bounds__(256) void k_score2(const unsigned short* __restrict__ Xhi,
                                                const unsigned* __restrict__ candi,
                                                unsigned* __restrict__ cnt,
                                                unsigned* __restrict__ glist) {
    int mg = blockIdx.x, chunk = P1CH + blockIdx.y, b = blockIdx.z;
    int tid = threadIdx.x;
    int w = tid >> 6, l = tid & 63;
    int lr = l & 31, lh = l >> 5;
    int m = mg * 128 + w * 32 + lr;
    int g = b * HW + m;
    int rowL = w * 32 + lr;                 // 0..127 local row
    const char* Xb = (const char*)(Xhi + (size_t)b * HW * C);

    __shared__ __align__(16) char tiles[2][8192];
    __shared__ unsigned lcnt[128];
    __shared__ unsigned lbuf[128][LCAP];    // 16 KB

    if (tid < 128) lcnt[tid] = 0u;

    // theta = 8th largest of union of the four sorted-desc phase-1 top-8 lists
    const unsigned* p1 = candi + (size_t)g * (P1CH * 8);
    unsigned t8[8], s8[8];
#pragma unroll
    for (int i = 0; i < 8; ++i) t8[i] = p1[i];
#pragma unroll
    for (int c = 1; c < P1CH; ++c) {
#pragma unroll
        for (int i = 0; i < 8; ++i) s8[i] = p1[c * 8 + i];
        merge8_desc(t8, s8);
    }
    float tf = __uint_as_float(t8[7] & 0xFFFFF800u) - 0.010f;
    unsigned thmb = __float_as_uint(tf);

    bf16x8 bf[4];
#pragma unroll
    for (int t = 0; t < 4; ++t)
        bf[t] = *(const bf16x8*)(Xb + (size_t)m * 128 + t * 32 + lh * 16);

    int swsrc = (tid * 16) ^ (((tid >> 3) & 7) << 4);
    int nC = chunk * CHUNK;

    GLOAD_LDS(Xb + (size_t)nC * 128 + swsrc, &tiles[0][w * 1024]);
    GLOAD_LDS(Xb + (size_t)nC * 128 + 4096 + swsrc, &tiles[0][4096 + w * 1024]);
    __syncthreads();   // covers lcnt init too

    const float BIAS = 1.0625f;
    const f32x16 cbias = {BIAS,BIAS,BIAS,BIAS,BIAS,BIAS,BIAS,BIAS,
                          BIAS,BIAS,BIAS,BIAS,BIAS,BIAS,BIAS,BIAS};

    for (int so = 0; so < NOUT; ++so) {
        if (so + 1 < NOUT) {
            const char* src = Xb + (size_t)(nC + (so + 1) * 64) * 128;
            GLOAD_LDS(src + swsrc, &tiles[(so + 1) & 1][w * 1024]);
            GLOAD_LDS(src + 4096 + swsrc, &tiles[(so + 1) & 1][4096 + w * 1024]);
        }
        const char* tile = tiles[so & 1];
#pragma unroll
        for (int h = 0; h < 2; ++h) {
            bf16x8 af0 = *(const bf16x8*)(tile + (h * 32 + lr) * 128 + ((lh * 16) ^ ((lr & 7) << 4)));
            f32x16 acc = __builtin_amdgcn_mfma_f32_32x32x16_bf16(af0, bf[0], cbias, 0, 0, 0);
#pragma unroll
            for (int t = 1; t < 4; ++t) {
                int o = t * 32 + lh * 16;
                bf16x8 af = *(const bf16x8*)(tile + (h * 32 + lr) * 128 + (o ^ ((lr & 7) << 4)));
                acc = __builtin_amdgcn_mfma_f32_32x32x16_bf16(af, bf[t], acc, 0, 0, 0);
            }
            int nbase = nC + so * 64 + h * 32 + 4 * lh;
#pragma unroll
            for (int r = 0; r < 16; ++r) {
                unsigned hb = __float_as_uint(acc[r]);
                if (hb > thmb) {
                    unsigned pos = atomicAdd(&lcnt[rowL], 1u);   // LDS atomic, cheap
                    if (pos < LCAP) {
                        unsigned nglob = (unsigned)(nbase + (r & 3) + 8 * (r >> 2));
                        lbuf[rowL][pos] = (hb & 0xFFFFC000u) | nglob;
                    }
                }
            }
        }
        __syncthreads();
    }

    // bulk flush: one global atomic per row, then copy
    if (tid < 128) {
        int gg = b * HW + mg * 128 + tid;
        unsigned lc = umin_(lcnt[tid], (unsigned)LCAP);
        if (lc) {
            unsigned base = atomicAdd(&cnt[gg], lc);
            for (unsigned j = 0; j < lc; ++j) {
                unsigned p = base + j;
                if (p < CAP) glist[(size_t)gg * CAP + p] = lbuf[tid][j];
            }
        }
    }
}

// ---------------- kernel 3: threshold-pruned exact fp32 rescore over p1 + appended records ----------------
__global__ __launch_bounds__(256) void k_rescore(const float* __restrict__ XT,
                                                 const float* __restrict__ invn,
                                                 const unsigned* __restrict__ candi,
                                                 const unsigned* __restrict__ cnt,
                                                 const unsigned* __restrict__ glist,
                                                 float* __restrict__ fvals,
                                                 int* __restrict__ fidx) {
    int g = blockIdx.x * 4 + (threadIdx.x >> 6);
    int l = threadIdx.x & 63;
    int b = g / HW, m = g - b * HW;
    const float* Xb = XT + (size_t)b * HW * C;
    float xml = Xb[(size_t)m * C + l];
    float vm = invn[g];

    int cn = (int)cnt[g];
    cn = cn < CAP ? cn : CAP;

    // 3 record slots/lane: idx = h*64 + l; idx<32 -> p1 (as set), else glist[idx-32]
    unsigned kr[3];
#pragma unroll
    for (int h = 0; h < 3; ++h) {
        int idx = h * 64 + l;
        if (idx < P1CH * 8) {
            unsigned key = candi[(size_t)g * (P1CH * 8) + idx];
            unsigned n = (unsigned)((idx >> 3) * CHUNK + (2047 - (int)(key & 0x7FFu)));
            kr[h] = (key & 0xFFFFC000u) | n;
        } else {
            int j = idx - P1CH * 8;
            kr[h] = (j < cn) ? glist[(size_t)g * CAP + j] : 0u;
        }
    }

    // radix search over score bits [30:14]: largest prefix with count >= 7
    unsigned thr = 0u;
#pragma unroll
    for (int bit = 30; bit >= 14; --bit) {
        unsigned cand = thr | (1u << bit);
        int c2 = __popcll(__ballot(kr[0] >= cand))
               + __popcll(__ballot(kr[1] >= cand))
               + __popcll(__ballot(kr[2] >= cand));
        if (c2 >= 7) thr = cand;
    }
    float s7 = __uint_as_float(thr);
    unsigned thk = __float_as_uint(s7 - 0.016f) & 0xFFFFC000u;

    float svv = -1e30f; int svi = 0x7fffffff;
    int nsurv = 0;
#pragma unroll
    for (int h = 0; h < 3; ++h) {
        unsigned long long bb = __ballot(kr[h] >= thk);
        while (bb) {
            int src = __builtin_ctzll(bb);
            bb &= bb - 1;
            unsigned key = (unsigned)__shfl((int)kr[h], src, 64);
            int ci = (int)(key & 0x3FFFu);
            float v = xml * Xb[(size_t)ci * C + l];
            v += __shfl_xor(v, 1, 64);  v += __shfl_xor(v, 2, 64);
            v += __shfl_xor(v, 4, 64);  v += __shfl_xor(v, 8, 64);
            v += __shfl_xor(v, 16, 64); v += __shfl_xor(v, 32, 64);
            if (l == nsurv) { svv = v * vm * invn[(size_t)b * HW + ci]; svi = ci; }
            ++nsurv;
        }
    }

    for (int s = 0; s < 7; ++s) {
        float bv = svv; int bi = svi;
#pragma unroll
        for (int d = 1; d < 64; d <<= 1) {
            float ov = __shfl_xor(bv, d, 64);
            int   oi = __shfl_xor(bi, d, 64);
            if (ov > bv || (ov == bv && oi < bi)) { bv = ov; bi = oi; }
        }
        if (l == 0) { fvals[(size_t)g * 7 + s] = bv; fidx[(size_t)g * 7 + s] = bi; }
        if (svi == bi) svv = -1e30f;
    }
}

// ---------------- kernel 4: bf16-MFMA conv: gather->LDS, D = Ga(64x448) x WbT^T(448x64) ----------------
__global__ __launch_bounds__(256) void k_out(const float* __restrict__ XT,
                                             const unsigned short* __restrict__ WbT,
                                             const float* __restrict__ fvals,
                                             const int* __restrict__ fidx,
                                             const float* __restrict__ bias,
                                             float* __restrict__ out) {
    int b = blockIdx.y;
    int m0 = blockIdx.x * 64;
    int tid = threadIdx.x;
    int w = tid >> 6, l = tid & 63;
    int lr = l & 31, hi = l >> 5;

    __shared__ __align__(16) unsigned short Ga[64][GA_STRIDE];  // 58.4 KB, bf16 [m][ik]
    __shared__ float Red[64][68];                               // 17.4 KB  [o][m]
    __shared__ int   fiL[64 * K];
    __shared__ float fvL[64 * K];

#pragma unroll
    for (int t = 0; t < 2; ++t) {
        int idx = t * 256 + tid;
        if (idx < 64 * K) {
            int gm = (b * HW + m0 + (idx / K)) * K + (idx % K);
            fiL[idx] = fidx[gm];
            fvL[idx] = fvals[gm];
        }
    }
    __syncthreads();

#pragma unroll
    for (int t = 0; t < 28; ++t) {
        int slot = t * 256 + tid;              // 7168 slots
        int r = slot >> 4, i4 = slot & 15;     // r = kq*64 + m
        int m = r & 63, kq = r >> 6;
        int n = fiL[m * K + kq];
        float vv = fvL[m * K + kq];
        float4 g = *(const float4*)&XT[((size_t)b * HW + n) * C + i4 * 4];
        unsigned short h0 = rne_bf16(g.x * vv), h1 = rne_bf16(g.y * vv);
        unsigned short h2 = rne_bf16(g.z * vv), h3 = rne_bf16(g.w * vv);
        unsigned p0 = (unsigned)h0 | ((unsigned)h1 << 16);
        unsigned p1 = (unsigned)h2 | ((unsigned)h3 << 16);
        uint2 p = {p0, p1};
        *(uint2*)&Ga[m][kq * 64 + i4 * 4] = p;
    }
    __syncthreads();

    int mt = w & 1, ct = w >> 1;
    int arow = mt * 32 + lr;
    int ocol = ct * 32 + lr;
    float bv = bias[ocol];
    f32x16 acc;
#pragma unroll
    for (int r = 0; r < 16; ++r) acc[r] = bv;

    const unsigned short* wrow = WbT + (size_t)ocol * IK;
#pragma unroll
    for (int s = 0; s < 28; ++s) {
        bf16x8 af = *(const bf16x8*)&Ga[arow][s * 16 + hi * 8];
        bf16x8 bf = *(const bf16x8*)&wrow[s * 16 + hi * 8];
        acc = __builtin_amdgcn_mfma_f32_32x32x16_bf16(af, bf, acc, 0, 0, 0);
    }

#pragma unroll
    for (int j = 0; j < 4; ++j) {
        float4 r4 = {acc[j * 4 + 0], acc[j * 4 + 1], acc[j * 4 + 2], acc[j * 4 + 3]};
        *(float4*)&Red[ocol][mt * 32 + j * 8 + hi * 4] = r4;
    }
    __syncthreads();

#pragma unroll
    for (int t = 0; t < 4; ++t) {
        int slot4 = t * 256 + tid;             // 1024 float4
        int o = slot4 >> 4, m4 = slot4 & 15;
        float4 v = *(const float4*)&Red[o][m4 * 4];
        v.x = v.x > 0.f ? v.x : 0.f;
        v.y = v.y > 0.f ? v.y : 0.f;
        v.z = v.z > 0.f ? v.z : 0.f;
        v.w = v.w > 0.f ? v.w : 0.f;
        *(float4*)&out[((size_t)b * C + o) * HW + m0 + m4 * 4] = v;
    }
}

extern "C" void kernel_launch(void* const* d_in, const int* in_sizes, int n_in,
                              void* d_out, int out_size, void* d_ws, size_t ws_size,
                              hipStream_t stream) {
    const float* x = (const float*)d_in[0];
    const float* W = (const float*)d_in[1];
    const float* bias = (const float*)d_in[2];
    float* out = (float*)d_out;

    float* ws = (float*)d_ws;
    float* XT = ws;                                        // B*HW*C f32
    unsigned short* Xhi = (unsigned short*)(XT + (size_t)BATCH * HW * C);   // B*HW*C bf16
    float* invn = (float*)(Xhi + (size_t)BATCH * HW * C);  // B*HW
    unsigned short* WbT = (unsigned short*)(invn + (size_t)BATCH * HW);     // C*IK bf16
    unsigned* candi = (unsigned*)(WbT + (size_t)C * IK + 64);               // B*HW*32 p1 keys
    unsigned* cnt = candi + (size_t)BATCH * HW * (P1CH * 8);                // B*HW
    unsigned* glist = cnt + (size_t)BATCH * HW;                             // B*HW*CAP
    float* fvals = (float*)(glist + (size_t)BATCH * HW * CAP);
    int* fidx = (int*)(fvals + (size_t)BATCH * HW * K);

    k_norm<<<dim3(HW / 64 + 28, BATCH), 256, 0, stream>>>(x, W, XT, Xhi, invn, WbT);
    k_score1<<<dim3(HW / 128, P1CH, BATCH), 256, 0, stream>>>(Xhi, candi, cnt);
    k_score2<<<dim3(HW / 128, NCH - P1CH, BATCH), 256, 0, stream>>>(Xhi, candi, cnt, glist);
    k_rescore<<<dim3(BATCH * HW / 4), 256, 0, stream>>>(XT, invn, candi, cnt, glist, fvals, fidx);
    k_out<<<dim3(HW / 64, BATCH), 256, 0, stream>>>(XT, WbT, fvals, fidx, bias, out);
}

// Round 15
// 144.547 us; speedup vs baseline: 1.4055x; 1.0164x over previous
//
#include <hip/hip_runtime.h>
#include <math.h>

#define HW 9216
#define C 64
#define BATCH 2
#define K 7
#define NCH 16
#define CHUNK 576            // HW/NCH
#define NOUT 9               // outer steps, 64 rows each
#define P1CH 4               // phase-1 chunks
#define CAP 160              // per-row global append capacity
#define LCAP 28              // per-row per-chunk LDS append capacity
#define IK 448               // K*C contraction length
#define GA_STRIDE 456        // IK + 8

typedef __attribute__((ext_vector_type(8))) short bf16x8;
typedef __attribute__((ext_vector_type(16))) float f32x16;

#define GLOAD_LDS(gp, lp) __builtin_amdgcn_global_load_lds( \
    (const __attribute__((address_space(1))) unsigned int*)(gp), \
    (__attribute__((address_space(3))) unsigned int*)(lp), 16, 0, 0)

__device__ __forceinline__ unsigned umax_(unsigned a, unsigned b) {
#if defined(__has_builtin) && __has_builtin(__builtin_elementwise_max)
    return __builtin_elementwise_max(a, b);
#else
    return a >= b ? a : b;
#endif
}
__device__ __forceinline__ unsigned umin_(unsigned a, unsigned b) {
#if defined(__has_builtin) && __has_builtin(__builtin_elementwise_min)
    return __builtin_elementwise_min(a, b);
#else
    return a >= b ? b : a;
#endif
}

__device__ __forceinline__ unsigned short rne_bf16(float f) {
    unsigned u = __float_as_uint(f);
    unsigned r = u + 0x7fffu + ((u >> 16) & 1u);
    return (unsigned short)(r >> 16);
}

// Batcher odd-even sort-8, descending, 19 CE
__device__ __forceinline__ void sort8_desc(unsigned (&k)[8]) {
#define CE8(i, j) { unsigned hi = umax_(k[i], k[j]); unsigned lo = umin_(k[i], k[j]); k[i] = hi; k[j] = lo; }
    CE8(0,1) CE8(2,3) CE8(4,5) CE8(6,7)
    CE8(0,2) CE8(1,3) CE8(4,6) CE8(5,7)
    CE8(1,2) CE8(5,6)
    CE8(0,4) CE8(1,5) CE8(2,6) CE8(3,7)
    CE8(2,4) CE8(3,5)
    CE8(1,2) CE8(3,4) CE8(5,6)
#undef CE8
}

// bitonic half-cleaner: sorts a bitonic 8-seq descending (12 CE)
__device__ __forceinline__ void clean8_desc(unsigned (&t)[8]) {
#define CET(i, j) { unsigned hi = umax_(t[i], t[j]); unsigned lo = umin_(t[i], t[j]); t[i] = hi; t[j] = lo; }
    CET(0,4) CET(1,5) CET(2,6) CET(3,7)
    CET(0,2) CET(1,3) CET(4,6) CET(5,7)
    CET(0,1) CET(2,3) CET(4,5) CET(6,7)
#undef CET
}

// tv (sorted desc) := top-8 of tv ∪ s (s sorted desc), sorted desc.
__device__ __forceinline__ void merge8_desc(unsigned (&tv)[8], const unsigned (&s)[8]) {
    unsigned t[8];
#pragma unroll
    for (int i = 0; i < 8; ++i) t[i] = umax_(tv[i], s[7 - i]);
    clean8_desc(t);
#pragma unroll
    for (int i = 0; i < 8; ++i) tv[i] = t[i];
}

// ---------------- kernel 1: normalize + transpose + bf16 (+ fused W->bf16 transpose) ----------------
__global__ __launch_bounds__(256) void k_norm(const float* __restrict__ x,
                                              const float* __restrict__ W,
                                              float* __restrict__ XT,
                                              unsigned short* __restrict__ Xhi,
                                              float* __restrict__ invn,
                                              unsigned short* __restrict__ WbT) {
    int b = blockIdx.y, tid = threadIdx.x;
    int bx = blockIdx.x;
    if (bx >= HW / 64) {
        if (b == 0) {
            int base = (bx - HW / 64) * 1024 + tid * 4;
#pragma unroll
            for (int j = 0; j < 4; ++j) {
                int idx = base + j;
                int o = idx / IK;
                int rem = idx - o * IK;
                int kq = rem >> 6, i = rem & 63;
                WbT[idx] = rne_bf16(W[(o * C + i) * K + kq]);
            }
        }
        return;
    }
    int m0 = bx * 64;
    __shared__ float T[64 * 65];
    __shared__ float ps[4][64];
    __shared__ float inv[64];
    const float* xb = x + (size_t)b * C * HW;
    for (int r = 0; r < 16; ++r) {
        int idx = r * 256 + tid; int c = idx >> 6, mm = idx & 63;
        T[c * 65 + mm] = xb[(size_t)c * HW + m0 + mm];
    }
    __syncthreads();
    int ml = tid & 63, part = tid >> 6;
    float s = 0.f;
    for (int c = part * 16; c < part * 16 + 16; ++c) { float v = T[c * 65 + ml]; s += v * v; }
    ps[part][ml] = s;
    __syncthreads();
    if (tid < 64) {
        float tot = ps[0][tid] + ps[1][tid] + ps[2][tid] + ps[3][tid];
        float iv = 1.0f / sqrtf(tot);
        inv[tid] = iv;
        invn[(size_t)b * HW + m0 + tid] = iv;
    }
    __syncthreads();
    for (int r = 0; r < 16; ++r) {
        int idx = r * 256 + tid; int row = idx >> 6, c = idx & 63;
        float uv = T[c * 65 + row];
        XT[((size_t)b * HW + m0 + row) * C + c] = uv;
        Xhi[((size_t)b * HW + m0 + row) * C + c] = rne_bf16(uv * inv[row]);
    }
}

// ---------------- kernel 2a: phase-1 scores (chunks 0..3): sort-merge top-8 per chunk ----------------
__global__ __launch_bounds__(256) void k_score1(const unsigned short* __restrict__ Xhi,
                                                unsigned* __restrict__ candi,
                                                unsigned* __restrict__ cnt) {
    int mg = blockIdx.x, chunk = blockIdx.y, b = blockIdx.z;
    int tid = threadIdx.x;
    if (chunk == 0 && tid < 128) cnt[b * HW + mg * 128 + tid] = 0u;
    int w = tid >> 6, l = tid & 63;
    int lr = l & 31, lh = l >> 5;
    int m = mg * 128 + w * 32 + lr;
    const char* Xb = (const char*)(Xhi + (size_t)b * HW * C);   // 128B rows

    __shared__ __align__(16) char tiles[2][8192];

    bf16x8 bf[4];
#pragma unroll
    for (int t = 0; t < 4; ++t)
        bf[t] = *(const bf16x8*)(Xb + (size_t)m * 128 + t * 32 + lh * 16);

    int swsrc = (tid * 16) ^ (((tid >> 3) & 7) << 4);
    int nC = chunk * CHUNK;

    GLOAD_LDS(Xb + (size_t)nC * 128 + swsrc, &tiles[0][w * 1024]);
    GLOAD_LDS(Xb + (size_t)nC * 128 + 4096 + swsrc, &tiles[0][4096 + w * 1024]);
    __syncthreads();

    unsigned tv[8];
#pragma unroll
    for (int j = 0; j < 8; ++j) tv[j] = 0u;

    const float BIAS = 1.0625f;
    const f32x16 cbias = {BIAS,BIAS,BIAS,BIAS,BIAS,BIAS,BIAS,BIAS,
                          BIAS,BIAS,BIAS,BIAS,BIAS,BIAS,BIAS,BIAS};

    for (int so = 0; so < NOUT; ++so) {
        if (so + 1 < NOUT) {
            const char* src = Xb + (size_t)(nC + (so + 1) * 64) * 128;
            GLOAD_LDS(src + swsrc, &tiles[(so + 1) & 1][w * 1024]);
            GLOAD_LDS(src + 4096 + swsrc, &tiles[(so + 1) & 1][4096 + w * 1024]);
        }
        const char* tile = tiles[so & 1];
#pragma unroll
        for (int h = 0; h < 2; ++h) {
            bf16x8 af0 = *(const bf16x8*)(tile + (h * 32 + lr) * 128 + ((lh * 16) ^ ((lr & 7) << 4)));
            f32x16 acc = __builtin_amdgcn_mfma_f32_32x32x16_bf16(af0, bf[0], cbias, 0, 0, 0);
#pragma unroll
            for (int t = 1; t < 4; ++t) {
                int o = t * 32 + lh * 16;
                bf16x8 af = *(const bf16x8*)(tile + (h * 32 + lr) * 128 + (o ^ ((lr & 7) << 4)));
                acc = __builtin_amdgcn_mfma_f32_32x32x16_bf16(af, bf[t], acc, 0, 0, 0);
            }
            unsigned inv_base = 2047u - (unsigned)(so * 64 + h * 32 + 4 * lh);
            unsigned ka[8], kb[8];
#pragma unroll
            for (int r = 0; r < 8; ++r) {
                ka[r] = (__float_as_uint(acc[r]) & 0xFFFFF800u)
                      | (inv_base - (unsigned)((r & 3) + 8 * (r >> 2)));
                kb[r] = (__float_as_uint(acc[r + 8]) & 0xFFFFF800u)
                      | (inv_base - (unsigned)(((r + 8) & 3) + 8 * ((r + 8) >> 2)));
            }
            sort8_desc(ka);
            sort8_desc(kb);
            merge8_desc(tv, ka);
            merge8_desc(tv, kb);
        }
        __syncthreads();
    }

    // cross-half-lane merge -> bitonic -> clean so the stored list is sorted desc
    unsigned pv[8];
#pragma unroll
    for (int j = 0; j < 8; ++j) pv[j] = tv[j];
#pragma unroll
    for (int j = 0; j < 8; ++j) {
        unsigned o = (unsigned)__shfl_xor((int)pv[7 - j], 32, 64);
        tv[j] = umax_(tv[j], o);
    }
    clean8_desc(tv);
    if (lh == 0) {
        size_t base = ((size_t)(b * HW + m) * P1CH + chunk) * 8;
#pragma unroll
        for (int j = 0; j < 8; ++j) candi[base + j] = tv[j];
    }
}

// ---------------- kernel 2b: phase-2 (chunks 4..15): theta-filter + branchless pair append ----------------
__global__ __launch_bounds__(256) void k_score2(const unsigned short* __restrict__ Xhi,
                                                const unsigned* __restrict__ candi,
                                                unsigned* __restrict__ cnt,
                                                unsigned* __restrict__ glist) {
    int mg = blockIdx.x, chunk = P1CH + blockIdx.y, b = blockIdx.z;
    int tid = threadIdx.x;
    int w = tid >> 6, l = tid & 63;
    int lr = l & 31, lh = l >> 5;
    int m = mg * 128 + w * 32 + lr;
    int g = b * HW + m;
    int rowL = w * 32 + lr;                 // 0..127 local row (2 lanes share: lh=0/1)
    const char* Xb = (const char*)(Xhi + (size_t)b * HW * C);

    __shared__ __align__(16) char tiles[2][8192];
    __shared__ unsigned lcnt[128];
    __shared__ unsigned lbuf[128][LCAP];    // 14 KB

    // theta = 8th largest of union of the four sorted-desc phase-1 top-8 lists
    const unsigned* p1 = candi + (size_t)g * (P1CH * 8);
    unsigned t8[8], s8[8];
#pragma unroll
    for (int i = 0; i < 8; ++i) t8[i] = p1[i];
#pragma unroll
    for (int c = 1; c < P1CH; ++c) {
#pragma unroll
        for (int i = 0; i < 8; ++i) s8[i] = p1[c * 8 + i];
        merge8_desc(t8, s8);
    }
    float tf = __uint_as_float(t8[7] & 0xFFFFF800u) - 0.014f;
    unsigned thmb = __float_as_uint(tf);

    bf16x8 bf[4];
#pragma unroll
    for (int t = 0; t < 4; ++t)
        bf[t] = *(const bf16x8*)(Xb + (size_t)m * 128 + t * 32 + lh * 16);

    int swsrc = (tid * 16) ^ (((tid >> 3) & 7) << 4);
    int nC = chunk * CHUNK;

    GLOAD_LDS(Xb + (size_t)nC * 128 + swsrc, &tiles[0][w * 1024]);
    GLOAD_LDS(Xb + (size_t)nC * 128 + 4096 + swsrc, &tiles[0][4096 + w * 1024]);
    __syncthreads();

    const float BIAS = 1.0625f;
    const f32x16 cbias = {BIAS,BIAS,BIAS,BIAS,BIAS,BIAS,BIAS,BIAS,
                          BIAS,BIAS,BIAS,BIAS,BIAS,BIAS,BIAS,BIAS};

    unsigned cntr = 0u;   // VGPR replica of the row's append count (both lanes agree)

    for (int so = 0; so < NOUT; ++so) {
        if (so + 1 < NOUT) {
            const char* src = Xb + (size_t)(nC + (so + 1) * 64) * 128;
            GLOAD_LDS(src + swsrc, &tiles[(so + 1) & 1][w * 1024]);
            GLOAD_LDS(src + 4096 + swsrc, &tiles[(so + 1) & 1][4096 + w * 1024]);
        }
        const char* tile = tiles[so & 1];
#pragma unroll
        for (int h = 0; h < 2; ++h) {
            bf16x8 af0 = *(const bf16x8*)(tile + (h * 32 + lr) * 128 + ((lh * 16) ^ ((lr & 7) << 4)));
            f32x16 acc = __builtin_amdgcn_mfma_f32_32x32x16_bf16(af0, bf[0], cbias, 0, 0, 0);
#pragma unroll
            for (int t = 1; t < 4; ++t) {
                int o = t * 32 + lh * 16;
                bf16x8 af = *(const bf16x8*)(tile + (h * 32 + lr) * 128 + (o ^ ((lr & 7) << 4)));
                acc = __builtin_amdgcn_mfma_f32_32x32x16_bf16(af, bf[t], acc, 0, 0, 0);
            }
            int nbase = nC + so * 64 + h * 32 + 4 * lh;
#pragma unroll
            for (int r = 0; r < 16; ++r) {
                unsigned hb = __float_as_uint(acc[r]);
                unsigned hit = hb > thmb ? 1u : 0u;
                unsigned hit_p = (unsigned)__shfl_xor((int)hit, 32, 64);
                unsigned pos = cntr + (lh ? hit_p : 0u);
                cntr += hit + hit_p;
                if (hit && pos < LCAP) {
                    unsigned nglob = (unsigned)(nbase + (r & 3) + 8 * (r >> 2));
                    lbuf[rowL][pos] = (hb & 0xFFFFC000u) | nglob;
                }
            }
        }
        __syncthreads();
    }

    if (lh == 0) lcnt[rowL] = umin_(cntr, (unsigned)LCAP);
    __syncthreads();

    // bulk flush: one global atomic per row, then copy
    if (tid < 128) {
        int gg = b * HW + mg * 128 + tid;
        unsigned lc = lcnt[tid];
        if (lc) {
            unsigned base = atomicAdd(&cnt[gg], lc);
            for (unsigned j = 0; j < lc; ++j) {
                unsigned p = base + j;
                if (p < CAP) glist[(size_t)gg * CAP + p] = lbuf[tid][j];
            }
        }
    }
}

// ---------------- kernel 3: pruned exact rescore, ballot-compacted + 16-lane-grouped ----------------
__global__ __launch_bounds__(256) void k_rescore(const float* __restrict__ XT,
                                                 const float* __restrict__ invn,
                                                 const unsigned* __restrict__ candi,
                                                 const unsigned* __restrict__ cnt,
                                                 const unsigned* __restrict__ glist,
                                                 float* __restrict__ fvals,
                                                 int* __restrict__ fidx) {
    int wv = threadIdx.x >> 6;
    int g = blockIdx.x * 4 + wv;
    int l = threadIdx.x & 63;
    int b = g / HW, m = g - b * HW;
    const float* Xb = XT + (size_t)b * HW * C;
    float vm = invn[g];

    __shared__ unsigned surv[4][128];
    __shared__ float sc[4][128];
    __shared__ int   sidx[4][128];

    int cn = (int)cnt[g];
    cn = cn < CAP ? cn : CAP;

    // 3 record slots/lane: idx = h*64 + l; idx<32 -> p1 (as set), else glist[idx-32]
    unsigned kr[3];
#pragma unroll
    for (int h = 0; h < 3; ++h) {
        int idx = h * 64 + l;
        if (idx < P1CH * 8) {
            unsigned key = candi[(size_t)g * (P1CH * 8) + idx];
            unsigned n = (unsigned)((idx >> 3) * CHUNK + (2047 - (int)(key & 0x7FFu)));
            kr[h] = (key & 0xFFFFC000u) | n;
        } else {
            int j = idx - P1CH * 8;
            kr[h] = (j < cn) ? glist[(size_t)g * CAP + j] : 0u;
        }
    }

    // radix search over score bits [30:14]: largest prefix with count >= 7
    unsigned thr = 0u;
#pragma unroll
    for (int bit = 30; bit >= 14; --bit) {
        unsigned cand = thr | (1u << bit);
        int c2 = __popcll(__ballot(kr[0] >= cand))
               + __popcll(__ballot(kr[1] >= cand))
               + __popcll(__ballot(kr[2] >= cand));
        if (c2 >= 7) thr = cand;
    }
    float s7 = __uint_as_float(thr);
    unsigned thk = __float_as_uint(s7 - 0.013f) & 0xFFFFC000u;

    // ballot-compact survivors into LDS (same-wave ordering, no atomics)
    unsigned long long ltmask = (l == 63) ? ~0ull >> 1 : ((1ull << l) - 1ull);
    int base = 0;
#pragma unroll
    for (int h = 0; h < 3; ++h) {
        bool hit = kr[h] >= thk;
        unsigned long long bb = __ballot(hit);
        int rank = __popcll(bb & ltmask);
        int pos = base + rank;
        if (hit && pos < 128) surv[wv][pos] = kr[h];
        base += __popcll(bb);
    }
    int ns = base < 128 ? base : 128;

    // grouped exact rescore: 4 candidates at a time, 16 lanes each
    int cl = l & 15, grp = l >> 4;
    float4 xm4 = *(const float4*)(Xb + (size_t)m * C + cl * 4);
    for (int j0 = 0; j0 < ns; j0 += 4) {
        int j = j0 + grp;
        bool act = j < ns;
        unsigned key = surv[wv][act ? j : 0];
        int ci = (int)(key & 0x3FFFu);
        float4 q4 = *(const float4*)(Xb + (size_t)ci * C + cl * 4);
        float s = xm4.x * q4.x + xm4.y * q4.y + xm4.z * q4.z + xm4.w * q4.w;
        s += __shfl_xor(s, 1, 64);
        s += __shfl_xor(s, 2, 64);
        s += __shfl_xor(s, 4, 64);
        s += __shfl_xor(s, 8, 64);
        if (cl == 0 && act) {
            sc[wv][j] = s * vm * invn[(size_t)b * HW + ci];
            sidx[wv][j] = ci;
        }
    }

    // top-7 selection over ns survivors (2 slots/lane)
    float sv[2]; int si[2];
    sv[0] = (l < ns) ? sc[wv][l] : -1e30f;
    si[0] = (l < ns) ? sidx[wv][l] : 0x7fffffff;
    sv[1] = (64 + l < ns) ? sc[wv][64 + l] : -1e30f;
    si[1] = (64 + l < ns) ? sidx[wv][64 + l] : 0x7fffffff;

    for (int s = 0; s < 7; ++s) {
        bool p0 = (sv[0] > sv[1]) || (sv[0] == sv[1] && si[0] < si[1]);
        float bv = p0 ? sv[0] : sv[1];
        int   bi = p0 ? si[0] : si[1];
#pragma unroll
        for (int d = 1; d < 64; d <<= 1) {
            float ov = __shfl_xor(bv, d, 64);
            int   oi = __shfl_xor(bi, d, 64);
            if (ov > bv || (ov == bv && oi < bi)) { bv = ov; bi = oi; }
        }
        if (l == 0) { fvals[(size_t)g * 7 + s] = bv; fidx[(size_t)g * 7 + s] = bi; }
        if (si[0] == bi) sv[0] = -1e30f;
        if (si[1] == bi) sv[1] = -1e30f;
    }
}

// ---------------- kernel 4: bf16-MFMA conv: gather->LDS, D = Ga(64x448) x WbT^T(448x64) ----------------
__global__ __launch_bounds__(256) void k_out(const float* __restrict__ XT,
                                             const unsigned short* __restrict__ WbT,
                                             const float* __restrict__ fvals,
                                             const int* __restrict__ fidx,
                                             const float* __restrict__ bias,
                                             float* __restrict__ out) {
    int b = blockIdx.y;
    int m0 = blockIdx.x * 64;
    int tid = threadIdx.x;
    int w = tid >> 6, l = tid & 63;
    int lr = l & 31, hi = l >> 5;

    __shared__ __align__(16) unsigned short Ga[64][GA_STRIDE];  // 58.4 KB, bf16 [m][ik]
    __shared__ float Red[64][68];                               // 17.4 KB  [o][m]
    __shared__ int   fiL[64 * K];
    __shared__ float fvL[64 * K];

#pragma unroll
    for (int t = 0; t < 2; ++t) {
        int idx = t * 256 + tid;
        if (idx < 64 * K) {
            int gm = (b * HW + m0 + (idx / K)) * K + (idx % K);
            fiL[idx] = fidx[gm];
            fvL[idx] = fvals[gm];
        }
    }
    __syncthreads();

#pragma unroll
    for (int t = 0; t < 28; ++t) {
        int slot = t * 256 + tid;              // 7168 slots
        int r = slot >> 4, i4 = slot & 15;     // r = kq*64 + m
        int m = r & 63, kq = r >> 6;
        int n = fiL[m * K + kq];
        float vv = fvL[m * K + kq];
        float4 g = *(const float4*)&XT[((size_t)b * HW + n) * C + i4 * 4];
        unsigned short h0 = rne_bf16(g.x * vv), h1 = rne_bf16(g.y * vv);
        unsigned short h2 = rne_bf16(g.z * vv), h3 = rne_bf16(g.w * vv);
        unsigned p0 = (unsigned)h0 | ((unsigned)h1 << 16);
        unsigned p1 = (unsigned)h2 | ((unsigned)h3 << 16);
        uint2 p = {p0, p1};
        *(uint2*)&Ga[m][kq * 64 + i4 * 4] = p;
    }
    __syncthreads();

    int mt = w & 1, ct = w >> 1;
    int arow = mt * 32 + lr;
    int ocol = ct * 32 + lr;
    float bv = bias[ocol];
    f32x16 acc;
#pragma unroll
    for (int r = 0; r < 16; ++r) acc[r] = bv;

    const unsigned short* wrow = WbT + (size_t)ocol * IK;
#pragma unroll
    for (int s = 0; s < 28; ++s) {
        bf16x8 af = *(const bf16x8*)&Ga[arow][s * 16 + hi * 8];
        bf16x8 bf = *(const bf16x8*)&wrow[s * 16 + hi * 8];
        acc = __builtin_amdgcn_mfma_f32_32x32x16_bf16(af, bf, acc, 0, 0, 0);
    }

#pragma unroll
    for (int j = 0; j < 4; ++j) {
        float4 r4 = {acc[j * 4 + 0], acc[j * 4 + 1], acc[j * 4 + 2], acc[j * 4 + 3]};
        *(float4*)&Red[ocol][mt * 32 + j * 8 + hi * 4] = r4;
    }
    __syncthreads();

#pragma unroll
    for (int t = 0; t < 4; ++t) {
        int slot4 = t * 256 + tid;             // 1024 float4
        int o = slot4 >> 4, m4 = slot4 & 15;
        float4 v = *(const float4*)&Red[o][m4 * 4];
        v.x = v.x > 0.f ? v.x : 0.f;
        v.y = v.y > 0.f ? v.y : 0.f;
        v.z = v.z > 0.f ? v.z : 0.f;
        v.w = v.w > 0.f ? v.w : 0.f;
        *(float4*)&out[((size_t)b * C + o) * HW + m0 + m4 * 4] = v;
    }
}

extern "C" void kernel_launch(void* const* d_in, const int* in_sizes, int n_in,
                              void* d_out, int out_size, void* d_ws, size_t ws_size,
                              hipStream_t stream) {
    const float* x = (const float*)d_in[0];
    const float* W = (const float*)d_in[1];
    const float* bias = (const float*)d_in[2];
    float* out = (float*)d_out;

    float* ws = (float*)d_ws;
    float* XT = ws;                                        // B*HW*C f32
    unsigned short* Xhi = (unsigned short*)(XT + (size_t)BATCH * HW * C);   // B*HW*C bf16
    float* invn = (float*)(Xhi + (size_t)BATCH * HW * C);  // B*HW
    unsigned short* WbT = (unsigned short*)(invn + (size_t)BATCH * HW);     // C*IK bf16
    unsigned* candi = (unsigned*)(WbT + (size_t)C * IK + 64);               // B*HW*32 p1 keys
    unsigned* cnt = candi + (size_t)BATCH * HW * (P1CH * 8);                // B*HW
    unsigned* glist = cnt + (size_t)BATCH * HW;                             // B*HW*CAP
    float* fvals = (float*)(glist + (size_t)BATCH * HW * CAP);
    int* fidx = (int*)(fvals + (size_t)BATCH * HW * K);

    k_norm<<<dim3(HW / 64 + 28, BATCH), 256, 0, stream>>>(x, W, XT, Xhi, invn, WbT);
    k_score1<<<dim3(HW / 128, P1CH, BATCH), 256, 0, stream>>>(Xhi, candi, cnt);
    k_score2<<<dim3(HW / 128, NCH - P1CH, BATCH), 256, 0, stream>>>(Xhi, candi, cnt, glist);
    k_rescore<<<dim3(BATCH * HW / 4), 256, 0, stream>>>(XT, invn, candi, cnt, glist, fvals, fidx);
    k_out<<<dim3(HW / 64, BATCH), 256, 0, stream>>>(XT, WbT, fvals, fidx, bias, out);
}

// Round 16
// 109.929 us; speedup vs baseline: 1.8481x; 1.3149x over previous
//
#include <hip/hip_runtime.h>
#include <math.h>

#define HW 9216
#define C 64
#define BATCH 2
#define K 7
#define NCH 16
#define CHUNK 576            // HW/NCH
#define NOUT 9               // outer steps, 64 rows each
#define LTOP 8               // per-chunk kept candidates
#define NCAND 128            // NCH*LTOP
#define IK 448               // K*C contraction length
#define GA_STRIDE 456        // IK + 8

typedef __attribute__((ext_vector_type(8))) short bf16x8;
typedef __attribute__((ext_vector_type(16))) float f32x16;

#define GLOAD_LDS(gp, lp) __builtin_amdgcn_global_load_lds( \
    (const __attribute__((address_space(1))) unsigned int*)(gp), \
    (__attribute__((address_space(3))) unsigned int*)(lp), 16, 0, 0)

__device__ __forceinline__ unsigned umax_(unsigned a, unsigned b) {
#if defined(__has_builtin) && __has_builtin(__builtin_elementwise_max)
    return __builtin_elementwise_max(a, b);
#else
    return a >= b ? a : b;
#endif
}
__device__ __forceinline__ unsigned umin_(unsigned a, unsigned b) {
#if defined(__has_builtin) && __has_builtin(__builtin_elementwise_min)
    return __builtin_elementwise_min(a, b);
#else
    return a >= b ? b : a;
#endif
}

__device__ __forceinline__ unsigned short rne_bf16(float f) {
    unsigned u = __float_as_uint(f);
    unsigned r = u + 0x7fffu + ((u >> 16) & 1u);
    return (unsigned short)(r >> 16);
}

// Batcher odd-even sort-8, descending, 19 CE
__device__ __forceinline__ void sort8_desc(unsigned (&k)[8]) {
#define CE8(i, j) { unsigned hi = umax_(k[i], k[j]); unsigned lo = umin_(k[i], k[j]); k[i] = hi; k[j] = lo; }
    CE8(0,1) CE8(2,3) CE8(4,5) CE8(6,7)
    CE8(0,2) CE8(1,3) CE8(4,6) CE8(5,7)
    CE8(1,2) CE8(5,6)
    CE8(0,4) CE8(1,5) CE8(2,6) CE8(3,7)
    CE8(2,4) CE8(3,5)
    CE8(1,2) CE8(3,4) CE8(5,6)
#undef CE8
}

// tv (sorted desc) := top-8 of tv ∪ s (s sorted desc), sorted desc.
__device__ __forceinline__ void merge8_desc(unsigned (&tv)[8], const unsigned (&s)[8]) {
    unsigned t[8];
#pragma unroll
    for (int i = 0; i < 8; ++i) t[i] = umax_(tv[i], s[7 - i]);
#define CET(i, j) { unsigned hi = umax_(t[i], t[j]); unsigned lo = umin_(t[i], t[j]); t[i] = hi; t[j] = lo; }
    CET(0,4) CET(1,5) CET(2,6) CET(3,7)
    CET(0,2) CET(1,3) CET(4,6) CET(5,7)
    CET(0,1) CET(2,3) CET(4,5) CET(6,7)
#undef CET
#pragma unroll
    for (int i = 0; i < 8; ++i) tv[i] = t[i];
}

// ---------------- kernel 1: normalize + transpose + bf16 (+ fused W->bf16 transpose) ----------------
__global__ __launch_bounds__(256) void k_norm(const float* __restrict__ x,
                                              const float* __restrict__ W,
                                              float* __restrict__ XT,
                                              unsigned short* __restrict__ Xhi,
                                              float* __restrict__ invn,
                                              unsigned short* __restrict__ WbT) {
    int b = blockIdx.y, tid = threadIdx.x;
    int bx = blockIdx.x;
    if (bx >= HW / 64) {
        // WbT[o][kq*64 + i] = bf16(W[(o*C + i)*K + kq]); 28672 elems over 28 blocks
        if (b == 0) {
            int base = (bx - HW / 64) * 1024 + tid * 4;
#pragma unroll
            for (int j = 0; j < 4; ++j) {
                int idx = base + j;
                int o = idx / IK;
                int rem = idx - o * IK;
                int kq = rem >> 6, i = rem & 63;
                WbT[idx] = rne_bf16(W[(o * C + i) * K + kq]);
            }
        }
        return;
    }
    int m0 = bx * 64;
    __shared__ float T[64 * 65];
    __shared__ float ps[4][64];
    __shared__ float inv[64];
    const float* xb = x + (size_t)b * C * HW;
    for (int r = 0; r < 16; ++r) {
        int idx = r * 256 + tid; int c = idx >> 6, mm = idx & 63;
        T[c * 65 + mm] = xb[(size_t)c * HW + m0 + mm];
    }
    __syncthreads();
    int ml = tid & 63, part = tid >> 6;
    float s = 0.f;
    for (int c = part * 16; c < part * 16 + 16; ++c) { float v = T[c * 65 + ml]; s += v * v; }
    ps[part][ml] = s;
    __syncthreads();
    if (tid < 64) {
        float tot = ps[0][tid] + ps[1][tid] + ps[2][tid] + ps[3][tid];
        float iv = 1.0f / sqrtf(tot);
        inv[tid] = iv;
        invn[(size_t)b * HW + m0 + tid] = iv;
    }
    __syncthreads();
    for (int r = 0; r < 16; ++r) {
        int idx = r * 256 + tid; int row = idx >> 6, c = idx & 63;
        float uv = T[c * 65 + row];
        XT[((size_t)b * HW + m0 + row) * C + c] = uv;
        Xhi[((size_t)b * HW + m0 + row) * C + c] = rne_bf16(uv * inv[row]);
    }
}

// ---------------- kernel 2: MFMA approx scores + batch sort-merge top-8 ----------------
__global__ __launch_bounds__(256) void k_score(const unsigned short* __restrict__ Xhi,
                                               unsigned* __restrict__ candi) {
    int mg = blockIdx.x, chunk = blockIdx.y, b = blockIdx.z;
    int tid = threadIdx.x;
    int w = tid >> 6, l = tid & 63;
    int lr = l & 31, lh = l >> 5;
    int m = mg * 128 + w * 32 + lr;
    const char* Xb = (const char*)(Xhi + (size_t)b * HW * C);   // 128B rows

    __shared__ __align__(16) char tiles[2][8192];

    bf16x8 bf[4];
#pragma unroll
    for (int t = 0; t < 4; ++t)
        bf[t] = *(const bf16x8*)(Xb + (size_t)m * 128 + t * 32 + lh * 16);

    int swsrc = (tid * 16) ^ (((tid >> 3) & 7) << 4);   // within first 4KB
    int nC = chunk * CHUNK;

    GLOAD_LDS(Xb + (size_t)nC * 128 + swsrc, &tiles[0][w * 1024]);
    GLOAD_LDS(Xb + (size_t)nC * 128 + 4096 + swsrc, &tiles[0][4096 + w * 1024]);
    __syncthreads();

    unsigned tv[LTOP];
#pragma unroll
    for (int j = 0; j < LTOP; ++j) tv[j] = 0u;

    const float BIAS = 1.0625f;
    const f32x16 cbias = {BIAS,BIAS,BIAS,BIAS,BIAS,BIAS,BIAS,BIAS,
                          BIAS,BIAS,BIAS,BIAS,BIAS,BIAS,BIAS,BIAS};

    for (int so = 0; so < NOUT; ++so) {
        if (so + 1 < NOUT) {
            const char* src = Xb + (size_t)(nC + (so + 1) * 64) * 128;
            GLOAD_LDS(src + swsrc, &tiles[(so + 1) & 1][w * 1024]);
            GLOAD_LDS(src + 4096 + swsrc, &tiles[(so + 1) & 1][4096 + w * 1024]);
        }
        const char* tile = tiles[so & 1];
#pragma unroll
        for (int h = 0; h < 2; ++h) {
            bf16x8 af0 = *(const bf16x8*)(tile + (h * 32 + lr) * 128 + ((lh * 16) ^ ((lr & 7) << 4)));
            f32x16 acc = __builtin_amdgcn_mfma_f32_32x32x16_bf16(af0, bf[0], cbias, 0, 0, 0);
#pragma unroll
            for (int t = 1; t < 4; ++t) {
                int o = t * 32 + lh * 16;
                bf16x8 af = *(const bf16x8*)(tile + (h * 32 + lr) * 128 + (o ^ ((lr & 7) << 4)));
                acc = __builtin_amdgcn_mfma_f32_32x32x16_bf16(af, bf[t], acc, 0, 0, 0);
            }
            unsigned inv_base = 2047u - (unsigned)(so * 64 + h * 32 + 4 * lh);
            unsigned ka[8], kb[8];
#pragma unroll
            for (int r = 0; r < 8; ++r) {
                ka[r] = (__float_as_uint(acc[r]) & 0xFFFFF800u)
                      | (inv_base - (unsigned)((r & 3) + 8 * (r >> 2)));
                kb[r] = (__float_as_uint(acc[r + 8]) & 0xFFFFF800u)
                      | (inv_base - (unsigned)(((r + 8) & 3) + 8 * ((r + 8) >> 2)));
            }
            sort8_desc(ka);
            sort8_desc(kb);
            merge8_desc(tv, ka);
            merge8_desc(tv, kb);
        }
        __syncthreads();
    }

    // bitonic partial merge with partner half-lane
    unsigned pv[LTOP];
#pragma unroll
    for (int j = 0; j < LTOP; ++j) pv[j] = tv[j];
#pragma unroll
    for (int j = 0; j < LTOP; ++j) {
        unsigned o = (unsigned)__shfl_xor((int)pv[LTOP - 1 - j], 32, 64);
        tv[j] = umax_(tv[j], o);
    }
    if (lh == 0) {
        size_t base = ((size_t)(b * HW + m) * NCH + chunk) * LTOP;
#pragma unroll
        for (int j = 0; j < LTOP; ++j) candi[base + j] = tv[j];
    }
}

// ---------------- kernel 3: pruned exact rescore, ballot-compacted + 16-lane-grouped ----------------
__global__ __launch_bounds__(256) void k_rescore(const float* __restrict__ XT,
                                                 const float* __restrict__ invn,
                                                 const unsigned* __restrict__ candi,
                                                 float* __restrict__ fvals,
                                                 int* __restrict__ fidx) {
    int wv = threadIdx.x >> 6;
    int g = blockIdx.x * 4 + wv;
    int l = threadIdx.x & 63;
    int b = g / HW, m = g - b * HW;
    const float* Xb = XT + (size_t)b * HW * C;
    float vm = invn[g];

    __shared__ unsigned surv[4][128];
    __shared__ float sc[4][128];
    __shared__ int   sidx[4][128];

    unsigned k0 = candi[(size_t)g * NCAND + l];
    unsigned k1 = candi[(size_t)g * NCAND + 64 + l];

    // radix binary search: largest 21-bit score prefix T with count(key >= T) >= 7
    unsigned thr = 0u;
#pragma unroll
    for (int bit = 30; bit >= 11; --bit) {    // scores < 4.0 -> bit31 always 0
        unsigned cand = thr | (1u << bit);
        int cnt = __popcll(__ballot(k0 >= cand)) + __popcll(__ballot(k1 >= cand));
        if (cnt >= 7) thr = cand;
    }
    float s7 = __uint_as_float(thr);
    unsigned thk = __float_as_uint(s7 - 0.012f) & 0xFFFFF800u;

    // ballot-compact survivors into LDS (stable within wave, no atomics)
    unsigned long long ltmask = (l == 63) ? (~0ull >> 1) : ((1ull << l) - 1ull);
    int base = 0;
    {
        bool hit = k0 >= thk;
        unsigned long long bb = __ballot(hit);
        int rank = __popcll(bb & ltmask);
        if (hit) { int ci = (l >> 3) * CHUNK + (2047 - (int)(k0 & 0x7FFu));
                   surv[wv][base + rank] = (unsigned)ci; }
        base += __popcll(bb);
    }
    {
        bool hit = k1 >= thk;
        unsigned long long bb = __ballot(hit);
        int rank = __popcll(bb & ltmask);
        if (hit) { int ci = ((64 + l) >> 3) * CHUNK + (2047 - (int)(k1 & 0x7FFu));
                   if (base + rank < 128) surv[wv][base + rank] = (unsigned)ci; }
        base += __popcll(bb);
    }
    int ns = base < 128 ? base : 128;

    // grouped exact rescore: 4 candidates at a time, 16 lanes each
    int cl = l & 15, grp = l >> 4;
    float4 xm4 = *(const float4*)(Xb + (size_t)m * C + cl * 4);
    for (int j0 = 0; j0 < ns; j0 += 4) {
        int j = j0 + grp;
        bool act = j < ns;
        int ci = (int)surv[wv][act ? j : 0];
        float4 q4 = *(const float4*)(Xb + (size_t)ci * C + cl * 4);
        float s = xm4.x * q4.x + xm4.y * q4.y + xm4.z * q4.z + xm4.w * q4.w;
        s += __shfl_xor(s, 1, 64);
        s += __shfl_xor(s, 2, 64);
        s += __shfl_xor(s, 4, 64);
        s += __shfl_xor(s, 8, 64);
        if (cl == 0 && act) {
            sc[wv][j] = s * vm * invn[(size_t)b * HW + ci];
            sidx[wv][j] = ci;
        }
    }

    // top-7 selection over ns survivors (2 slots/lane)
    float sv[2]; int si[2];
    sv[0] = (l < ns) ? sc[wv][l] : -1e30f;
    si[0] = (l < ns) ? sidx[wv][l] : 0x7fffffff;
    sv[1] = (64 + l < ns) ? sc[wv][64 + l] : -1e30f;
    si[1] = (64 + l < ns) ? sidx[wv][64 + l] : 0x7fffffff;

    for (int s = 0; s < 7; ++s) {
        bool p0 = (sv[0] > sv[1]) || (sv[0] == sv[1] && si[0] < si[1]);
        float bv = p0 ? sv[0] : sv[1];
        int   bi = p0 ? si[0] : si[1];
#pragma unroll
        for (int d = 1; d < 64; d <<= 1) {
            float ov = __shfl_xor(bv, d, 64);
            int   oi = __shfl_xor(bi, d, 64);
            if (ov > bv || (ov == bv && oi < bi)) { bv = ov; bi = oi; }
        }
        if (l == 0) { fvals[(size_t)g * 7 + s] = bv; fidx[(size_t)g * 7 + s] = bi; }
        if (si[0] == bi) sv[0] = -1e30f;
        if (si[1] == bi) sv[1] = -1e30f;
    }
}

// ---------------- kernel 4: bf16-MFMA conv: gather->LDS, D = Ga(64x448) x WbT^T(448x64) ----------------
__global__ __launch_bounds__(256) void k_out(const float* __restrict__ XT,
                                             const unsigned short* __restrict__ WbT,
                                             const float* __restrict__ fvals,
                                             const int* __restrict__ fidx,
                                             const float* __restrict__ bias,
                                             float* __restrict__ out) {
    int b = blockIdx.y;
    int m0 = blockIdx.x * 64;
    int tid = threadIdx.x;
    int w = tid >> 6, l = tid & 63;
    int lr = l & 31, hi = l >> 5;

    __shared__ __align__(16) unsigned short Ga[64][GA_STRIDE];  // 58.4 KB, bf16 [m][ik]
    __shared__ float Red[64][68];                               // 17.4 KB  [o][m]
    __shared__ int   fiL[64 * K];
    __shared__ float fvL[64 * K];

#pragma unroll
    for (int t = 0; t < 2; ++t) {
        int idx = t * 256 + tid;
        if (idx < 64 * K) {
            int gm = (b * HW + m0 + (idx / K)) * K + (idx % K);
            fiL[idx] = fidx[gm];
            fvL[idx] = fvals[gm];
        }
    }
    __syncthreads();

#pragma unroll
    for (int t = 0; t < 28; ++t) {
        int slot = t * 256 + tid;              // 7168 slots
        int r = slot >> 4, i4 = slot & 15;     // r = kq*64 + m
        int m = r & 63, kq = r >> 6;
        int n = fiL[m * K + kq];
        float vv = fvL[m * K + kq];
        float4 g = *(const float4*)&XT[((size_t)b * HW + n) * C + i4 * 4];
        unsigned short h0 = rne_bf16(g.x * vv), h1 = rne_bf16(g.y * vv);
        unsigned short h2 = rne_bf16(g.z * vv), h3 = rne_bf16(g.w * vv);
        unsigned p0 = (unsigned)h0 | ((unsigned)h1 << 16);
        unsigned p1 = (unsigned)h2 | ((unsigned)h3 << 16);
        uint2 p = {p0, p1};
        *(uint2*)&Ga[m][kq * 64 + i4 * 4] = p;
    }
    __syncthreads();

    int mt = w & 1, ct = w >> 1;
    int arow = mt * 32 + lr;
    int ocol = ct * 32 + lr;
    float bv = bias[ocol];
    f32x16 acc;
#pragma unroll
    for (int r = 0; r < 16; ++r) acc[r] = bv;

    const unsigned short* wrow = WbT + (size_t)ocol * IK;
#pragma unroll
    for (int s = 0; s < 28; ++s) {
        bf16x8 af = *(const bf16x8*)&Ga[arow][s * 16 + hi * 8];
        bf16x8 bf = *(const bf16x8*)&wrow[s * 16 + hi * 8];
        acc = __builtin_amdgcn_mfma_f32_32x32x16_bf16(af, bf, acc, 0, 0, 0);
    }

#pragma unroll
    for (int j = 0; j < 4; ++j) {
        float4 r4 = {acc[j * 4 + 0], acc[j * 4 + 1], acc[j * 4 + 2], acc[j * 4 + 3]};
        *(float4*)&Red[ocol][mt * 32 + j * 8 + hi * 4] = r4;
    }
    __syncthreads();

#pragma unroll
    for (int t = 0; t < 4; ++t) {
        int slot4 = t * 256 + tid;             // 1024 float4
        int o = slot4 >> 4, m4 = slot4 & 15;
        float4 v = *(const float4*)&Red[o][m4 * 4];
        v.x = v.x > 0.f ? v.x : 0.f;
        v.y = v.y > 0.f ? v.y : 0.f;
        v.z = v.z > 0.f ? v.z : 0.f;
        v.w = v.w > 0.f ? v.w : 0.f;
        *(float4*)&out[((size_t)b * C + o) * HW + m0 + m4 * 4] = v;
    }
}

extern "C" void kernel_launch(void* const* d_in, const int* in_sizes, int n_in,
                              void* d_out, int out_size, void* d_ws, size_t ws_size,
                              hipStream_t stream) {
    const float* x = (const float*)d_in[0];
    const float* W = (const float*)d_in[1];
    const float* bias = (const float*)d_in[2];
    float* out = (float*)d_out;

    float* ws = (float*)d_ws;
    float* XT = ws;                                        // B*HW*C f32
    unsigned short* Xhi = (unsigned short*)(XT + (size_t)BATCH * HW * C);   // B*HW*C bf16
    float* invn = (float*)(Xhi + (size_t)BATCH * HW * C);  // B*HW
    unsigned short* WbT = (unsigned short*)(invn + (size_t)BATCH * HW);     // C*IK bf16
    unsigned* candi = (unsigned*)(WbT + (size_t)C * IK + 64);               // B*HW*NCAND
    float* fvals = (float*)(candi + (size_t)BATCH * HW * NCAND);
    int* fidx = (int*)(fvals + (size_t)BATCH * HW * K);

    k_norm<<<dim3(HW / 64 + 28, BATCH), 256, 0, stream>>>(x, W, XT, Xhi, invn, WbT);
    k_score<<<dim3(HW / 128, NCH, BATCH), 256, 0, stream>>>(Xhi, candi);
    k_rescore<<<dim3(BATCH * HW / 4), 256, 0, stream>>>(XT, invn, candi, fvals, fidx);
    k_out<<<dim3(HW / 64, BATCH), 256, 0, stream>>>(XT, WbT, fvals, fidx, bias, out);
}

// Round 17
// 106.697 us; speedup vs baseline: 1.9041x; 1.0303x over previous
//
#include <hip/hip_runtime.h>
#include <math.h>

#define HW 9216
#define C 64
#define BATCH 2
#define K 7
#define NCH 16
#define CHUNK 576            // HW/NCH
#define NOUT 9               // outer steps, 64 rows each
#define LTOP 8               // per-chunk kept candidates
#define NCAND 128            // NCH*LTOP
#define IK 448               // K*C contraction length
#define GA_STRIDE 456        // IK + 8
#define MO 32                // m-rows per k_out block

typedef __attribute__((ext_vector_type(8))) short bf16x8;
typedef __attribute__((ext_vector_type(16))) float f32x16;

#define GLOAD_LDS(gp, lp) __builtin_amdgcn_global_load_lds( \
    (const __attribute__((address_space(1))) unsigned int*)(gp), \
    (__attribute__((address_space(3))) unsigned int*)(lp), 16, 0, 0)

__device__ __forceinline__ unsigned umax_(unsigned a, unsigned b) {
#if defined(__has_builtin) && __has_builtin(__builtin_elementwise_max)
    return __builtin_elementwise_max(a, b);
#else
    return a >= b ? a : b;
#endif
}
__device__ __forceinline__ unsigned umin_(unsigned a, unsigned b) {
#if defined(__has_builtin) && __has_builtin(__builtin_elementwise_min)
    return __builtin_elementwise_min(a, b);
#else
    return a >= b ? b : a;
#endif
}

__device__ __forceinline__ unsigned short rne_bf16(float f) {
    unsigned u = __float_as_uint(f);
    unsigned r = u + 0x7fffu + ((u >> 16) & 1u);
    return (unsigned short)(r >> 16);
}

// Batcher odd-even sort-8, descending, 19 CE
__device__ __forceinline__ void sort8_desc(unsigned (&k)[8]) {
#define CE8(i, j) { unsigned hi = umax_(k[i], k[j]); unsigned lo = umin_(k[i], k[j]); k[i] = hi; k[j] = lo; }
    CE8(0,1) CE8(2,3) CE8(4,5) CE8(6,7)
    CE8(0,2) CE8(1,3) CE8(4,6) CE8(5,7)
    CE8(1,2) CE8(5,6)
    CE8(0,4) CE8(1,5) CE8(2,6) CE8(3,7)
    CE8(2,4) CE8(3,5)
    CE8(1,2) CE8(3,4) CE8(5,6)
#undef CE8
}

// tv (sorted desc) := top-8 of tv ∪ s (s sorted desc), sorted desc.
__device__ __forceinline__ void merge8_desc(unsigned (&tv)[8], const unsigned (&s)[8]) {
    unsigned t[8];
#pragma unroll
    for (int i = 0; i < 8; ++i) t[i] = umax_(tv[i], s[7 - i]);
#define CET(i, j) { unsigned hi = umax_(t[i], t[j]); unsigned lo = umin_(t[i], t[j]); t[i] = hi; t[j] = lo; }
    CET(0,4) CET(1,5) CET(2,6) CET(3,7)
    CET(0,2) CET(1,3) CET(4,6) CET(5,7)
    CET(0,1) CET(2,3) CET(4,5) CET(6,7)
#undef CET
#pragma unroll
    for (int i = 0; i < 8; ++i) tv[i] = t[i];
}

// ---------------- kernel 1: normalize + transpose + bf16 (+ fused W->bf16 transpose) ----------------
__global__ __launch_bounds__(256) void k_norm(const float* __restrict__ x,
                                              const float* __restrict__ W,
                                              float* __restrict__ XT,
                                              unsigned short* __restrict__ Xhi,
                                              float* __restrict__ invn,
                                              unsigned short* __restrict__ WbT) {
    int b = blockIdx.y, tid = threadIdx.x;
    int bx = blockIdx.x;
    if (bx >= HW / 64) {
        // WbT[o][kq*64 + i] = bf16(W[(o*C + i)*K + kq]); 28672 elems over 28 blocks
        if (b == 0) {
            int base = (bx - HW / 64) * 1024 + tid * 4;
#pragma unroll
            for (int j = 0; j < 4; ++j) {
                int idx = base + j;
                int o = idx / IK;
                int rem = idx - o * IK;
                int kq = rem >> 6, i = rem & 63;
                WbT[idx] = rne_bf16(W[(o * C + i) * K + kq]);
            }
        }
        return;
    }
    int m0 = bx * 64;
    __shared__ float T[64 * 65];   // stride 65: conflict-free column reads
    __shared__ float ps[4][64];
    __shared__ float inv[64];
    const float* xb = x + (size_t)b * C * HW;

    // vectorized load: 1024 float4 = 64 c x 16 m-quads
#pragma unroll
    for (int r = 0; r < 4; ++r) {
        int idx = r * 256 + tid;
        int c = idx >> 4, m4 = idx & 15;
        float4 v = *(const float4*)&xb[(size_t)c * HW + m0 + m4 * 4];
        T[c * 65 + m4 * 4 + 0] = v.x;
        T[c * 65 + m4 * 4 + 1] = v.y;
        T[c * 65 + m4 * 4 + 2] = v.z;
        T[c * 65 + m4 * 4 + 3] = v.w;
    }
    __syncthreads();
    int ml = tid & 63, part = tid >> 6;
    float s = 0.f;
    for (int c = part * 16; c < part * 16 + 16; ++c) { float v = T[c * 65 + ml]; s += v * v; }
    ps[part][ml] = s;
    __syncthreads();
    if (tid < 64) {
        float tot = ps[0][tid] + ps[1][tid] + ps[2][tid] + ps[3][tid];
        float iv = 1.0f / sqrtf(tot);
        inv[tid] = iv;
        invn[(size_t)b * HW + m0 + tid] = iv;
    }
    __syncthreads();

    // vectorized stores: 1024 slots = 64 rows x 16 c-quads
#pragma unroll
    for (int r = 0; r < 4; ++r) {
        int idx = r * 256 + tid;
        int row = idx >> 4, c4 = idx & 15;
        float iv = inv[row];
        float4 u;
        u.x = T[(c4 * 4 + 0) * 65 + row];
        u.y = T[(c4 * 4 + 1) * 65 + row];
        u.z = T[(c4 * 4 + 2) * 65 + row];
        u.w = T[(c4 * 4 + 3) * 65 + row];
        *(float4*)&XT[((size_t)b * HW + m0 + row) * C + c4 * 4] = u;
        unsigned short h0 = rne_bf16(u.x * iv), h1 = rne_bf16(u.y * iv);
        unsigned short h2 = rne_bf16(u.z * iv), h3 = rne_bf16(u.w * iv);
        uint2 p = {(unsigned)h0 | ((unsigned)h1 << 16), (unsigned)h2 | ((unsigned)h3 << 16)};
        *(uint2*)&Xhi[((size_t)b * HW + m0 + row) * C + c4 * 4] = p;
    }
}

// ---------------- kernel 2: MFMA approx scores + batch sort-merge top-8 ----------------
__global__ __launch_bounds__(256) void k_score(const unsigned short* __restrict__ Xhi,
                                               unsigned* __restrict__ candi) {
    int mg = blockIdx.x, chunk = blockIdx.y, b = blockIdx.z;
    int tid = threadIdx.x;
    int w = tid >> 6, l = tid & 63;
    int lr = l & 31, lh = l >> 5;
    int m = mg * 128 + w * 32 + lr;
    const char* Xb = (const char*)(Xhi + (size_t)b * HW * C);   // 128B rows

    __shared__ __align__(16) char tiles[2][8192];

    bf16x8 bf[4];
#pragma unroll
    for (int t = 0; t < 4; ++t)
        bf[t] = *(const bf16x8*)(Xb + (size_t)m * 128 + t * 32 + lh * 16);

    int swsrc = (tid * 16) ^ (((tid >> 3) & 7) << 4);   // within first 4KB
    int nC = chunk * CHUNK;

    GLOAD_LDS(Xb + (size_t)nC * 128 + swsrc, &tiles[0][w * 1024]);
    GLOAD_LDS(Xb + (size_t)nC * 128 + 4096 + swsrc, &tiles[0][4096 + w * 1024]);
    __syncthreads();

    unsigned tv[LTOP];
#pragma unroll
    for (int j = 0; j < LTOP; ++j) tv[j] = 0u;

    const float BIAS = 1.0625f;
    const f32x16 cbias = {BIAS,BIAS,BIAS,BIAS,BIAS,BIAS,BIAS,BIAS,
                          BIAS,BIAS,BIAS,BIAS,BIAS,BIAS,BIAS,BIAS};

    for (int so = 0; so < NOUT; ++so) {
        if (so + 1 < NOUT) {
            const char* src = Xb + (size_t)(nC + (so + 1) * 64) * 128;
            GLOAD_LDS(src + swsrc, &tiles[(so + 1) & 1][w * 1024]);
            GLOAD_LDS(src + 4096 + swsrc, &tiles[(so + 1) & 1][4096 + w * 1024]);
        }
        const char* tile = tiles[so & 1];
#pragma unroll
        for (int h = 0; h < 2; ++h) {
            bf16x8 af0 = *(const bf16x8*)(tile + (h * 32 + lr) * 128 + ((lh * 16) ^ ((lr & 7) << 4)));
            f32x16 acc = __builtin_amdgcn_mfma_f32_32x32x16_bf16(af0, bf[0], cbias, 0, 0, 0);
#pragma unroll
            for (int t = 1; t < 4; ++t) {
                int o = t * 32 + lh * 16;
                bf16x8 af = *(const bf16x8*)(tile + (h * 32 + lr) * 128 + (o ^ ((lr & 7) << 4)));
                acc = __builtin_amdgcn_mfma_f32_32x32x16_bf16(af, bf[t], acc, 0, 0, 0);
            }
            unsigned inv_base = 2047u - (unsigned)(so * 64 + h * 32 + 4 * lh);
            unsigned ka[8], kb[8];
#pragma unroll
            for (int r = 0; r < 8; ++r) {
                ka[r] = (__float_as_uint(acc[r]) & 0xFFFFF800u)
                      | (inv_base - (unsigned)((r & 3) + 8 * (r >> 2)));
                kb[r] = (__float_as_uint(acc[r + 8]) & 0xFFFFF800u)
                      | (inv_base - (unsigned)(((r + 8) & 3) + 8 * ((r + 8) >> 2)));
            }
            sort8_desc(ka);
            sort8_desc(kb);
            merge8_desc(tv, ka);
            merge8_desc(tv, kb);
        }
        __syncthreads();
    }

    // bitonic partial merge with partner half-lane
    unsigned pv[LTOP];
#pragma unroll
    for (int j = 0; j < LTOP; ++j) pv[j] = tv[j];
#pragma unroll
    for (int j = 0; j < LTOP; ++j) {
        unsigned o = (unsigned)__shfl_xor((int)pv[LTOP - 1 - j], 32, 64);
        tv[j] = umax_(tv[j], o);
    }
    if (lh == 0) {
        size_t base = ((size_t)(b * HW + m) * NCH + chunk) * LTOP;
#pragma unroll
        for (int j = 0; j < LTOP; ++j) candi[base + j] = tv[j];
    }
}

// ---------------- kernel 3: pruned exact rescore, ballot-compacted + 16-lane-grouped ----------------
__global__ __launch_bounds__(256) void k_rescore(const float* __restrict__ XT,
                                                 const float* __restrict__ invn,
                                                 const unsigned* __restrict__ candi,
                                                 float* __restrict__ fvals,
                                                 int* __restrict__ fidx) {
    int wv = threadIdx.x >> 6;
    int g = blockIdx.x * 4 + wv;
    int l = threadIdx.x & 63;
    int b = g / HW, m = g - b * HW;
    const float* Xb = XT + (size_t)b * HW * C;
    float vm = invn[g];

    __shared__ unsigned surv[4][128];
    __shared__ float sc[4][128];
    __shared__ int   sidx[4][128];

    unsigned k0 = candi[(size_t)g * NCAND + l];
    unsigned k1 = candi[(size_t)g * NCAND + 64 + l];

    // radix binary search: largest 21-bit score prefix T with count(key >= T) >= 7
    unsigned thr = 0u;
#pragma unroll
    for (int bit = 30; bit >= 11; --bit) {    // scores < 4.0 -> bit31 always 0
        unsigned cand = thr | (1u << bit);
        int cnt = __popcll(__ballot(k0 >= cand)) + __popcll(__ballot(k1 >= cand));
        if (cnt >= 7) thr = cand;
    }
    float s7 = __uint_as_float(thr);
    unsigned thk = __float_as_uint(s7 - 0.012f) & 0xFFFFF800u;

    // ballot-compact survivors into LDS (stable within wave, no atomics)
    unsigned long long ltmask = (l == 63) ? (~0ull >> 1) : ((1ull << l) - 1ull);
    int base = 0;
    {
        bool hit = k0 >= thk;
        unsigned long long bb = __ballot(hit);
        int rank = __popcll(bb & ltmask);
        if (hit) { int ci = (l >> 3) * CHUNK + (2047 - (int)(k0 & 0x7FFu));
                   surv[wv][base + rank] = (unsigned)ci; }
        base += __popcll(bb);
    }
    {
        bool hit = k1 >= thk;
        unsigned long long bb = __ballot(hit);
        int rank = __popcll(bb & ltmask);
        if (hit) { int ci = ((64 + l) >> 3) * CHUNK + (2047 - (int)(k1 & 0x7FFu));
                   if (base + rank < 128) surv[wv][base + rank] = (unsigned)ci; }
        base += __popcll(bb);
    }
    int ns = base < 128 ? base : 128;

    // grouped exact rescore: 4 candidates at a time, 16 lanes each
    int cl = l & 15, grp = l >> 4;
    float4 xm4 = *(const float4*)(Xb + (size_t)m * C + cl * 4);
    for (int j0 = 0; j0 < ns; j0 += 4) {
        int j = j0 + grp;
        bool act = j < ns;
        int ci = (int)surv[wv][act ? j : 0];
        float4 q4 = *(const float4*)(Xb + (size_t)ci * C + cl * 4);
        float s = xm4.x * q4.x + xm4.y * q4.y + xm4.z * q4.z + xm4.w * q4.w;
        s += __shfl_xor(s, 1, 64);
        s += __shfl_xor(s, 2, 64);
        s += __shfl_xor(s, 4, 64);
        s += __shfl_xor(s, 8, 64);
        if (cl == 0 && act) {
            sc[wv][j] = s * vm * invn[(size_t)b * HW + ci];
            sidx[wv][j] = ci;
        }
    }

    // top-7 selection over ns survivors (2 slots/lane)
    float sv[2]; int si[2];
    sv[0] = (l < ns) ? sc[wv][l] : -1e30f;
    si[0] = (l < ns) ? sidx[wv][l] : 0x7fffffff;
    sv[1] = (64 + l < ns) ? sc[wv][64 + l] : -1e30f;
    si[1] = (64 + l < ns) ? sidx[wv][64 + l] : 0x7fffffff;

    for (int s = 0; s < 7; ++s) {
        bool p0 = (sv[0] > sv[1]) || (sv[0] == sv[1] && si[0] < si[1]);
        float bv = p0 ? sv[0] : sv[1];
        int   bi = p0 ? si[0] : si[1];
#pragma unroll
        for (int d = 1; d < 64; d <<= 1) {
            float ov = __shfl_xor(bv, d, 64);
            int   oi = __shfl_xor(bi, d, 64);
            if (ov > bv || (ov == bv && oi < bi)) { bv = ov; bi = oi; }
        }
        if (l == 0) { fvals[(size_t)g * 7 + s] = bv; fidx[(size_t)g * 7 + s] = bi; }
        if (si[0] == bi) sv[0] = -1e30f;
        if (si[1] == bi) sv[1] = -1e30f;
    }
}

// ---------------- kernel 4: bf16-MFMA conv, 32-row tiles: D = Ga(32x448) x WbT^T(448x64) ----------------
// 576 blocks; 4 waves = 2 o-tiles x 2 K-halves; bias folded into kh=0 accumulator.
__global__ __launch_bounds__(256) void k_out(const float* __restrict__ XT,
                                             const unsigned short* __restrict__ WbT,
                                             const float* __restrict__ fvals,
                                             const int* __restrict__ fidx,
                                             const float* __restrict__ bias,
                                             float* __restrict__ out) {
    int b = blockIdx.y;
    int m0 = blockIdx.x * MO;
    int tid = threadIdx.x;
    int w = tid >> 6, l = tid & 63;
    int lr = l & 31, hi = l >> 5;

    __shared__ __align__(16) unsigned short Ga[MO][GA_STRIDE];  // 29.2 KB, bf16 [m][ik]
    __shared__ float Red[2][64][36];                            // 18.4 KB  [kh][o][m]
    __shared__ int   fiL[MO * K];
    __shared__ float fvL[MO * K];

    if (tid < MO * K) {
        int gm = (b * HW + m0 + (tid / K)) * K + (tid % K);
        fiL[tid] = fidx[gm];
        fvL[tid] = fvals[gm];
    }
    __syncthreads();

    // gather + scale + bf16 -> Ga ; 224 rows x 16 slots, coalesced float4 reads
#pragma unroll
    for (int t = 0; t < 14; ++t) {
        int slot = t * 256 + tid;              // 3584 slots
        int r = slot >> 4, i4 = slot & 15;     // r = kq*32 + m
        int m = r & 31, kq = r >> 5;
        int n = fiL[m * K + kq];
        float vv = fvL[m * K + kq];
        float4 g = *(const float4*)&XT[((size_t)b * HW + n) * C + i4 * 4];
        unsigned short h0 = rne_bf16(g.x * vv), h1 = rne_bf16(g.y * vv);
        unsigned short h2 = rne_bf16(g.z * vv), h3 = rne_bf16(g.w * vv);
        unsigned p0 = (unsigned)h0 | ((unsigned)h1 << 16);
        unsigned p1 = (unsigned)h2 | ((unsigned)h3 << 16);
        uint2 p = {p0, p1};
        *(uint2*)&Ga[m][kq * 64 + i4 * 4] = p;
    }
    __syncthreads();

    int ow = w & 1, kh = w >> 1;
    int arow = lr;
    int ocol = ow * 32 + lr;
    float bv = (kh == 0) ? bias[ocol] : 0.f;
    f32x16 acc;
#pragma unroll
    for (int r = 0; r < 16; ++r) acc[r] = bv;

    const unsigned short* wrow = WbT + (size_t)ocol * IK;
#pragma unroll
    for (int si = 0; si < 14; ++si) {
        int s = kh * 14 + si;
        bf16x8 af = *(const bf16x8*)&Ga[arow][s * 16 + hi * 8];
        bf16x8 bfr = *(const bf16x8*)&wrow[s * 16 + hi * 8];
        acc = __builtin_amdgcn_mfma_f32_32x32x16_bf16(af, bfr, acc, 0, 0, 0);
    }

#pragma unroll
    for (int j = 0; j < 4; ++j) {
        float4 r4 = {acc[j * 4 + 0], acc[j * 4 + 1], acc[j * 4 + 2], acc[j * 4 + 3]};
        *(float4*)&Red[kh][ocol][j * 8 + hi * 4] = r4;
    }
    __syncthreads();

    // epilogue: 2048 floats = 64 o x 32 m; sum K-halves + relu, coalesced over m
#pragma unroll
    for (int t = 0; t < 2; ++t) {
        int slot4 = t * 256 + tid;             // 512 float4
        int o = slot4 >> 3, m4 = slot4 & 7;
        float4 a = *(const float4*)&Red[0][o][m4 * 4];
        float4 c = *(const float4*)&Red[1][o][m4 * 4];
        float4 v = {a.x + c.x, a.y + c.y, a.z + c.z, a.w + c.w};
        v.x = v.x > 0.f ? v.x : 0.f;
        v.y = v.y > 0.f ? v.y : 0.f;
        v.z = v.z > 0.f ? v.z : 0.f;
        v.w = v.w > 0.f ? v.w : 0.f;
        *(float4*)&out[((size_t)b * C + o) * HW + m0 + m4 * 4] = v;
    }
}

extern "C" void kernel_launch(void* const* d_in, const int* in_sizes, int n_in,
                              void* d_out, int out_size, void* d_ws, size_t ws_size,
                              hipStream_t stream) {
    const float* x = (const float*)d_in[0];
    const float* W = (const float*)d_in[1];
    const float* bias = (const float*)d_in[2];
    float* out = (float*)d_out;

    float* ws = (float*)d_ws;
    float* XT = ws;                                        // B*HW*C f32
    unsigned short* Xhi = (unsigned short*)(XT + (size_t)BATCH * HW * C);   // B*HW*C bf16
    float* invn = (float*)(Xhi + (size_t)BATCH * HW * C);  // B*HW
    unsigned short* WbT = (unsigned short*)(invn + (size_t)BATCH * HW);     // C*IK bf16
    unsigned* candi = (unsigned*)(WbT + (size_t)C * IK + 64);               // B*HW*NCAND
    float* fvals = (float*)(candi + (size_t)BATCH * HW * NCAND);
    int* fidx = (int*)(fvals + (size_t)BATCH * HW * K);

    k_norm<<<dim3(HW / 64 + 28, BATCH), 256, 0, stream>>>(x, W, XT, Xhi, invn, WbT);
    k_score<<<dim3(HW / 128, NCH, BATCH), 256, 0, stream>>>(Xhi, candi);
    k_rescore<<<dim3(BATCH * HW / 4), 256, 0, stream>>>(XT, invn, candi, fvals, fidx);
    k_out<<<dim3(HW / MO, BATCH), 256, 0, stream>>>(XT, WbT, fvals, fidx, bias, out);
}